// Round 1
// baseline (3491.876 us; speedup 1.0000x reference)
//
#include <hip/hip_runtime.h>

#define BN_EPS 1e-5f

// ---------------- classifier 1x1 conv + spatial max (cls) ----------------
__global__ __launch_bounds__(256) void k_classifier(const float* __restrict__ x4,
    const float* __restrict__ Wc, float* __restrict__ fsmall, float* __restrict__ cls){
  int nc = blockIdx.x; int n = nc / 20, c = nc % 20;
  __shared__ float wc[512];
  for (int k = threadIdx.x; k < 512; k += 256) wc[k] = Wc[c * 512 + k];
  __syncthreads();
  int p = threadIdx.x;                       // 16x16 = 256 spatial positions
  const float* xp = x4 + (size_t)n * 512 * 256 + p;
  float acc = 0.f;
  #pragma unroll 8
  for (int k = 0; k < 512; k++) acc = fmaf(xp[(size_t)k * 256], wc[k], acc);
  fsmall[((size_t)n * 20 + c) * 256 + p] = acc;
  // block max-reduce
  float m = acc;
  for (int off = 32; off > 0; off >>= 1) m = fmaxf(m, __shfl_down(m, off, 64));
  __shared__ float wmax[4];
  if ((threadIdx.x & 63) == 0) wmax[threadIdx.x >> 6] = m;
  __syncthreads();
  if (threadIdx.x == 0)
    cls[n * 20 + c] = fmaxf(fmaxf(wmax[0], wmax[1]), fmaxf(wmax[2], wmax[3]));
}

// ---------------- resize x 512->256 (jax bilinear WITH antialias: 4-tap) ----------------
__global__ __launch_bounds__(256) void k_resize_x(const float* __restrict__ x, float* __restrict__ xs){
  int idx = blockIdx.x * 256 + threadIdx.x;   // 8*3*65536 total
  int p = idx & 65535; int img = idx >> 16;   // img = n*3+ch
  int y = p >> 8, xo = p & 255;
  const float* src = x + (size_t)img * 512 * 512;
  const float w4[4] = {0.125f, 0.375f, 0.375f, 0.125f};
  float acc = 0.f, wsum = 0.f;
  #pragma unroll
  for (int ty = 0; ty < 4; ty++){
    int sy = 2 * y - 1 + ty; if (sy < 0 || sy > 511) continue;
    #pragma unroll
    for (int tx = 0; tx < 4; tx++){
      int sx = 2 * xo - 1 + tx; if (sx < 0 || sx > 511) continue;
      float w = w4[ty] * w4[tx];
      acc += w * src[sy * 512 + sx]; wsum += w;
    }
  }
  xs[idx] = acc / wsum;
}

// ---------------- conv1 3x3 (3->100) + ReLU + BN1 ----------------
__global__ __launch_bounds__(256) void k_conv1(const float* __restrict__ xs,
    const float* __restrict__ W1, const float* __restrict__ b1,
    const float* __restrict__ g1, const float* __restrict__ be1,
    const float* __restrict__ m1, const float* __restrict__ v1,
    float* __restrict__ y1){
  int n = blockIdx.z; int ty0 = blockIdx.y * 16, tx0 = blockIdx.x * 16;
  __shared__ float tile[3][18][18];
  for (int i = threadIdx.x; i < 3 * 324; i += 256){
    int ch = i / 324, r = i % 324;
    int yy = r / 18 - 1 + ty0, xx = r % 18 - 1 + tx0;
    float v = 0.f;
    if (yy >= 0 && yy < 256 && xx >= 0 && xx < 256)
      v = xs[((size_t)n * 3 + ch) * 65536 + yy * 256 + xx];
    tile[ch][r / 18][r % 18] = v;
  }
  __syncthreads();
  int ly = threadIdx.x >> 4, lx = threadIdx.x & 15;
  float acc[100];
  #pragma unroll
  for (int o = 0; o < 100; o++) acc[o] = 0.f;
  for (int ch = 0; ch < 3; ch++){
    float in[9];
    #pragma unroll
    for (int k = 0; k < 9; k++) in[k] = tile[ch][ly + k / 3][lx + k % 3];
    #pragma unroll
    for (int o = 0; o < 100; o++){
      #pragma unroll
      for (int k = 0; k < 9; k++)
        acc[o] = fmaf(in[k], W1[(o * 3 + ch) * 9 + k], acc[o]);
    }
  }
  int p = (ty0 + ly) * 256 + tx0 + lx;
  #pragma unroll
  for (int o = 0; o < 100; o++){
    float val = fmaxf(acc[o] + b1[o], 0.f);
    float sc = g1[o] / sqrtf(v1[o] + BN_EPS);
    y1[((size_t)n * 100 + o) * 65536 + p] = (val - m1[o]) * sc + be1[o];
  }
}

// ---------------- conv2 3x3 (100->100)+ReLU+BN2, fused conv3 1x1(100->32)+BN3, mask + argmax ----------------
__global__ __launch_bounds__(256) void k_conv2(const float* __restrict__ y1,
    const float* __restrict__ W2, const float* __restrict__ b2,
    const float* __restrict__ g2, const float* __restrict__ be2,
    const float* __restrict__ m2, const float* __restrict__ v2,
    const float* __restrict__ W3, const float* __restrict__ b3,
    const float* __restrict__ g3, const float* __restrict__ be3,
    const float* __restrict__ m3, const float* __restrict__ v3,
    float* __restrict__ mask_out, int* __restrict__ maskobj){
  int n = blockIdx.z; int ty0 = blockIdx.y * 16, tx0 = blockIdx.x * 16;
  __shared__ float tile[18][18];
  int ly = threadIdx.x >> 4, lx = threadIdx.x & 15;
  float acc[100];
  #pragma unroll
  for (int o = 0; o < 100; o++) acc[o] = 0.f;
  for (int ic = 0; ic < 100; ic++){
    __syncthreads();
    for (int i = threadIdx.x; i < 324; i += 256){
      int yy = i / 18 - 1 + ty0, xx = i % 18 - 1 + tx0;
      float v = 0.f;
      if (yy >= 0 && yy < 256 && xx >= 0 && xx < 256)
        v = y1[((size_t)n * 100 + ic) * 65536 + yy * 256 + xx];
      tile[i / 18][i % 18] = v;
    }
    __syncthreads();
    float in[9];
    #pragma unroll
    for (int k = 0; k < 9; k++) in[k] = tile[ly + k / 3][lx + k % 3];
    const float* w = W2 + ic * 9;      // W2[o][ic][k] = W2[o*900 + ic*9 + k]
    #pragma unroll
    for (int o = 0; o < 100; o++){
      #pragma unroll
      for (int k = 0; k < 9; k++)
        acc[o] = fmaf(in[k], w[o * 900 + k], acc[o]);
    }
  }
  // ReLU + BN2 -> y2 (kept in regs)
  #pragma unroll
  for (int o = 0; o < 100; o++){
    float val = fmaxf(acc[o] + b2[o], 0.f);
    float sc = g2[o] / sqrtf(v2[o] + BN_EPS);
    acc[o] = (val - m2[o]) * sc + be2[o];
  }
  int p = (ty0 + ly) * 256 + tx0 + lx;
  float best = -3.4e38f; int bi = 0;
  for (int od = 0; od < 32; od++){
    float t = b3[od];
    #pragma unroll
    for (int c = 0; c < 100; c++) t = fmaf(acc[c], W3[od * 100 + c], t);
    float sc = g3[od] / sqrtf(v3[od] + BN_EPS);
    float mv = (t - m3[od]) * sc + be3[od];
    mask_out[((size_t)n * 32 + od) * 65536 + p] = mv;
    if (mv > best){ best = mv; bi = od; }     // strict > : first-max wins (jnp.argmax)
  }
  maskobj[n * 65536 + p] = bi;
}

// ---------------- per-tile segment partial sums (features resized on the fly) ----------------
__global__ __launch_bounds__(256) void k_segsum(const int* __restrict__ maskobj,
    const float* __restrict__ fsmall, float* __restrict__ psum, float* __restrict__ pcnt){
  int b = blockIdx.x; int n = b >> 8; int p0 = (b & 255) * 256;
  __shared__ float lsum[640];
  __shared__ float lcnt[32];
  for (int i = threadIdx.x; i < 640; i += 256) lsum[i] = 0.f;
  if (threadIdx.x < 32) lcnt[threadIdx.x] = 0.f;
  __syncthreads();
  int p = p0 + threadIdx.x;
  int id = maskobj[n * 65536 + p];
  atomicAdd(&lcnt[id], 1.f);
  int y = p >> 8, xo = p & 255;
  // bilinear upscale 16->256, half-pixel, edge-clamped
  float syf = (y + 0.5f) * 0.0625f - 0.5f; int sy0 = (int)floorf(syf); float fy = syf - sy0;
  int y0 = max(sy0, 0), y1i = min(sy0 + 1, 15);
  float sxf = (xo + 0.5f) * 0.0625f - 0.5f; int sx0 = (int)floorf(sxf); float fx = sxf - sx0;
  int x0 = max(sx0, 0), x1i = min(sx0 + 1, 15);
  const float* fs = fsmall + (size_t)n * 20 * 256;
  for (int c = 0; c < 20; c++){
    const float* F = fs + c * 256;
    float v = (1.f - fy) * ((1.f - fx) * F[y0 * 16 + x0] + fx * F[y0 * 16 + x1i])
            +        fy  * ((1.f - fx) * F[y1i * 16 + x0] + fx * F[y1i * 16 + x1i]);
    atomicAdd(&lsum[id * 20 + c], v);
  }
  __syncthreads();
  for (int i = threadIdx.x; i < 640; i += 256) psum[(size_t)b * 640 + i] = lsum[i];
  if (threadIdx.x < 32) pcnt[(size_t)b * 32 + threadIdx.x] = lcnt[threadIdx.x];
}

// ---------------- reduce partials -> sums/cnt ----------------
__global__ __launch_bounds__(256) void k_reduce(const float* __restrict__ psum,
    const float* __restrict__ pcnt, float* __restrict__ sums, float* __restrict__ cnt){
  int idx = blockIdx.x * 256 + threadIdx.x;   // < 5120
  int n = idx / 640, r = idx % 640;
  float s = 0.f;
  for (int b = 0; b < 256; b++) s += psum[((size_t)n * 256 + b) * 640 + r];
  sums[idx] = s;
  if (idx < 256){
    int n2 = idx >> 5, s2 = idx & 31;
    float c = 0.f;
    for (int b = 0; b < 256; b++) c += pcnt[((size_t)n2 * 256 + b) * 32 + s2];
    cnt[idx] = c;
  }
}

// ---------------- means + cls_fea ----------------
__global__ __launch_bounds__(256) void k_means(const float* __restrict__ sums,
    const float* __restrict__ cnt, float* __restrict__ means, float* __restrict__ cls_fea){
  __shared__ float lm[5120];
  __shared__ float lc[256];
  int s = threadIdx.x;
  lc[s] = cnt[s];
  float c = fmaxf(lc[s], 1.f);
  for (int ch = 0; ch < 20; ch++){
    float m = sums[s * 20 + ch] / c;
    lm[s * 20 + ch] = m;
    means[s * 20 + ch] = m;
  }
  __syncthreads();
  if (s < 160){
    int n = s / 20, ch = s % 20;
    float m = -3.4e38f;
    for (int seg = 0; seg < 32; seg++){
      int g = n * 32 + seg;
      if (lc[g] > 0.f) m = fmaxf(m, lm[g * 20 + ch]);
    }
    cls_fea[s] = m;
  }
}

// ---------------- scatter means -> features output ----------------
__global__ __launch_bounds__(256) void k_scatter(const int* __restrict__ maskobj,
    const float* __restrict__ means, float* __restrict__ feat_out){
  int idx = blockIdx.x * 256 + threadIdx.x;   // 8*65536
  int n = idx >> 16, p = idx & 65535;
  int id = maskobj[idx];
  const float* mrow = means + (n * 32 + id) * 20;
  #pragma unroll
  for (int c = 0; c < 20; c++)
    feat_out[((size_t)n * 20 + c) * 65536 + p] = mrow[c];
}

extern "C" void kernel_launch(void* const* d_in, const int* in_sizes, int n_in,
                              void* d_out, int out_size, void* d_ws, size_t ws_size,
                              hipStream_t stream) {
  const float* x   = (const float*)d_in[0];
  const float* x4  = (const float*)d_in[1];
  const float* Wc  = (const float*)d_in[2];
  const float* W1  = (const float*)d_in[3];
  const float* b1  = (const float*)d_in[4];
  const float* g1  = (const float*)d_in[5];
  const float* be1 = (const float*)d_in[6];
  const float* m1  = (const float*)d_in[7];
  const float* v1  = (const float*)d_in[8];
  const float* W2  = (const float*)d_in[9];
  const float* b2  = (const float*)d_in[10];
  const float* g2  = (const float*)d_in[11];
  const float* be2 = (const float*)d_in[12];
  const float* m2  = (const float*)d_in[13];
  const float* v2  = (const float*)d_in[14];
  const float* W3  = (const float*)d_in[15];
  const float* b3  = (const float*)d_in[16];
  const float* g3  = (const float*)d_in[17];
  const float* be3 = (const float*)d_in[18];
  const float* m3  = (const float*)d_in[19];
  const float* v3  = (const float*)d_in[20];

  float* out = (float*)d_out;
  float* cls_out  = out;                 // [8,20]
  float* clsf_out = out + 160;           // [8,20]
  float* feat_out = out + 320;           // [8,20,256,256]
  float* mask_out = out + 320 + 10485760; // [8,32,256,256]

  float* wsf = (float*)d_ws;
  float* xs      = wsf;                          // 1,572,864
  float* fsmall  = wsf + 1572864;                // 40,960
  float* y1      = wsf + 1613824;                // 52,428,800
  int*   maskobj = (int*)(wsf + 54042624);       // 524,288
  float* psum    = wsf + 54566912;               // 1,310,720
  float* pcnt    = wsf + 55877632;               // 65,536
  float* sums    = wsf + 55943168;               // 5,120
  float* cnt     = wsf + 55948288;               // 256
  float* means   = wsf + 55948544;               // 5,120

  k_classifier<<<160, 256, 0, stream>>>(x4, Wc, fsmall, cls_out);
  k_resize_x<<<6144, 256, 0, stream>>>(x, xs);
  k_conv1<<<dim3(16, 16, 8), 256, 0, stream>>>(xs, W1, b1, g1, be1, m1, v1, y1);
  k_conv2<<<dim3(16, 16, 8), 256, 0, stream>>>(y1, W2, b2, g2, be2, m2, v2,
                                               W3, b3, g3, be3, m3, v3,
                                               mask_out, maskobj);
  k_segsum<<<2048, 256, 0, stream>>>(maskobj, fsmall, psum, pcnt);
  k_reduce<<<20, 256, 0, stream>>>(psum, pcnt, sums, cnt);
  k_means<<<1, 256, 0, stream>>>(sums, cnt, means, clsf_out);
  k_scatter<<<2048, 256, 0, stream>>>(maskobj, means, feat_out);
}

// Round 2
// 2566.346 us; speedup vs baseline: 1.3606x; 1.3606x over previous
//
#include <hip/hip_runtime.h>

#define BN_EPS 1e-5f

// ---------------- classifier 1x1 conv + spatial max (cls) ----------------
__global__ __launch_bounds__(256) void k_classifier(const float* __restrict__ x4,
    const float* __restrict__ Wc, float* __restrict__ fsmall, float* __restrict__ cls){
  int nc = blockIdx.x; int n = nc / 20, c = nc % 20;
  __shared__ float wc[512];
  for (int k = threadIdx.x; k < 512; k += 256) wc[k] = Wc[c * 512 + k];
  __syncthreads();
  int p = threadIdx.x;                       // 16x16 = 256 spatial positions
  const float* xp = x4 + (size_t)n * 512 * 256 + p;
  float acc = 0.f;
  #pragma unroll 8
  for (int k = 0; k < 512; k++) acc = fmaf(xp[(size_t)k * 256], wc[k], acc);
  fsmall[((size_t)n * 20 + c) * 256 + p] = acc;
  // block max-reduce
  float m = acc;
  for (int off = 32; off > 0; off >>= 1) m = fmaxf(m, __shfl_down(m, off, 64));
  __shared__ float wmax[4];
  if ((threadIdx.x & 63) == 0) wmax[threadIdx.x >> 6] = m;
  __syncthreads();
  if (threadIdx.x == 0)
    cls[n * 20 + c] = fmaxf(fmaxf(wmax[0], wmax[1]), fmaxf(wmax[2], wmax[3]));
}

// ---------------- resize x 512->256 (jax bilinear WITH antialias: 4-tap) ----------------
__global__ __launch_bounds__(256) void k_resize_x(const float* __restrict__ x, float* __restrict__ xs){
  int idx = blockIdx.x * 256 + threadIdx.x;   // 8*3*65536 total
  int p = idx & 65535; int img = idx >> 16;   // img = n*3+ch
  int y = p >> 8, xo = p & 255;
  const float* src = x + (size_t)img * 512 * 512;
  const float w4[4] = {0.125f, 0.375f, 0.375f, 0.125f};
  float acc = 0.f, wsum = 0.f;
  #pragma unroll
  for (int ty = 0; ty < 4; ty++){
    int sy = 2 * y - 1 + ty; if (sy < 0 || sy > 511) continue;
    #pragma unroll
    for (int tx = 0; tx < 4; tx++){
      int sx = 2 * xo - 1 + tx; if (sx < 0 || sx > 511) continue;
      float w = w4[ty] * w4[tx];
      acc += w * src[sy * 512 + sx]; wsum += w;
    }
  }
  xs[idx] = acc / wsum;
}

// ---------------- conv1 3x3 (3->100) + ReLU + BN1 (4 passes of 25 och, no spills) ----------------
__global__ __launch_bounds__(256) void k_conv1(const float* __restrict__ xs,
    const float* __restrict__ W1, const float* __restrict__ b1,
    const float* __restrict__ g1, const float* __restrict__ be1,
    const float* __restrict__ m1, const float* __restrict__ v1,
    float* __restrict__ y1){
  int n = blockIdx.z; int ty0 = blockIdx.y * 16, tx0 = blockIdx.x * 16;
  __shared__ float tile[3][18][19];
  for (int i = threadIdx.x; i < 3 * 324; i += 256){
    int ch = i / 324, r = i % 324;
    int yy = r / 18 - 1 + ty0, xx = r % 18 - 1 + tx0;
    float v = 0.f;
    if (yy >= 0 && yy < 256 && xx >= 0 && xx < 256)
      v = xs[((size_t)n * 3 + ch) * 65536 + yy * 256 + xx];
    tile[ch][r / 18][r % 18] = v;
  }
  __syncthreads();
  int ly = threadIdx.x >> 4, lx = threadIdx.x & 15;
  int p = (ty0 + ly) * 256 + tx0 + lx;
  float in[3][9];
  #pragma unroll
  for (int ch = 0; ch < 3; ch++)
    #pragma unroll
    for (int k = 0; k < 9; k++) in[ch][k] = tile[ch][ly + k / 3][lx + k % 3];
  for (int pass = 0; pass < 4; pass++){
    float acc[25];
    #pragma unroll
    for (int o = 0; o < 25; o++) acc[o] = 0.f;
    #pragma unroll
    for (int ch = 0; ch < 3; ch++){
      #pragma unroll
      for (int o = 0; o < 25; o++){
        int oc = pass * 25 + o;
        #pragma unroll
        for (int k = 0; k < 9; k++)
          acc[o] = fmaf(in[ch][k], W1[(oc * 3 + ch) * 9 + k], acc[o]);
      }
    }
    #pragma unroll
    for (int o = 0; o < 25; o++){
      int oc = pass * 25 + o;
      float val = fmaxf(acc[o] + b1[oc], 0.f);
      float sc = g1[oc] / sqrtf(v1[oc] + BN_EPS);
      y1[((size_t)n * 100 + oc) * 65536 + p] = (val - m1[oc]) * sc + be1[oc];
    }
  }
}

// ---------------- conv2 3x3 (100->100)+ReLU+BN2, fused conv3 1x1(100->32)+BN3, mask + argmax ----
// Block: 8x8 pixel tile, 4 waves. Wave w computes out-channels [25w, 25w+25) for all 64 px
// (1 px per thread, acc[25] -> stays in VGPRs; weights wave-uniform -> s_load).
__global__ __launch_bounds__(256) void k_conv2(const float* __restrict__ y1,
    const float* __restrict__ W2, const float* __restrict__ b2,
    const float* __restrict__ g2, const float* __restrict__ be2,
    const float* __restrict__ m2, const float* __restrict__ v2,
    const float* __restrict__ W3, const float* __restrict__ b3,
    const float* __restrict__ g3, const float* __restrict__ be3,
    const float* __restrict__ m3, const float* __restrict__ v3,
    float* __restrict__ mask_out, int* __restrict__ maskobj){
  int n = blockIdx.z;
  int ty0 = blockIdx.y * 8, tx0 = blockIdx.x * 8;
  int lane = threadIdx.x & 63;
  int wv = __builtin_amdgcn_readfirstlane(threadIdx.x >> 6);  // 0..3, SGPR
  int ly = lane >> 3, lx = lane & 7;

  __shared__ float tile[10][12];     // 10x10 halo tile, stride 12 (<=2-way bank alias = free)
  __shared__ float y2[100][64];      // 25.6 KB: BN2'd activations for conv3
  __shared__ float abest[4][64];
  __shared__ int   aidx[4][64];

  float acc[25];
  #pragma unroll
  for (int o = 0; o < 25; o++) acc[o] = 0.f;

  const float* w2base = W2 + (size_t)(wv * 25) * 900;   // wave-uniform
  for (int ic = 0; ic < 100; ic++){
    __syncthreads();
    if (threadIdx.x < 100){
      int r = threadIdx.x / 10, cc = threadIdx.x % 10;
      int yy = ty0 + r - 1, xx = tx0 + cc - 1;
      float v = 0.f;
      if (yy >= 0 && yy < 256 && xx >= 0 && xx < 256)
        v = y1[((size_t)n * 100 + ic) * 65536 + yy * 256 + xx];
      tile[r][cc] = v;
    }
    __syncthreads();
    float in[9];
    #pragma unroll
    for (int k = 0; k < 9; k++) in[k] = tile[ly + k / 3][lx + k % 3];
    const float* w = w2base + ic * 9;
    #pragma unroll
    for (int o = 0; o < 25; o++){
      #pragma unroll
      for (int k = 0; k < 9; k++)
        acc[o] = fmaf(in[k], w[o * 900 + k], acc[o]);
    }
  }

  // ReLU + BN2 -> y2 in LDS
  #pragma unroll
  for (int o = 0; o < 25; o++){
    int oc = wv * 25 + o;
    float val = fmaxf(acc[o] + b2[oc], 0.f);
    float sc = g2[oc] / sqrtf(v2[oc] + BN_EPS);
    y2[oc][lane] = (val - m2[oc]) * sc + be2[oc];
  }
  __syncthreads();

  // conv3 1x1 (100->32) + BN3: wave w computes od in [8w, 8w+8) for its pixel (= lane)
  float t[8];
  #pragma unroll
  for (int j = 0; j < 8; j++) t[j] = b3[wv * 8 + j];
  for (int c = 0; c < 100; c++){
    float v = y2[c][lane];
    #pragma unroll
    for (int j = 0; j < 8; j++)
      t[j] = fmaf(v, W3[(wv * 8 + j) * 100 + c], t[j]);
  }
  int py = ty0 + ly, px = tx0 + lx;
  size_t pix = (size_t)py * 256 + px;
  float best = -3.4e38f; int bi = 0;
  #pragma unroll
  for (int j = 0; j < 8; j++){
    int od = wv * 8 + j;
    float sc = g3[od] / sqrtf(v3[od] + BN_EPS);
    float mv = (t[j] - m3[od]) * sc + be3[od];
    mask_out[((size_t)n * 32 + od) * 65536 + pix] = mv;
    if (mv > best){ best = mv; bi = od; }   // strict >: first-max within chunk
  }
  abest[wv][lane] = best; aidx[wv][lane] = bi;
  __syncthreads();
  if (threadIdx.x < 64){
    float bb = abest[0][lane]; int ii = aidx[0][lane];
    #pragma unroll
    for (int w2i = 1; w2i < 4; w2i++){
      float v = abest[w2i][lane];
      if (v > bb){ bb = v; ii = aidx[w2i][lane]; }  // ascending chunk order => first-max
    }
    maskobj[(size_t)n * 65536 + pix] = ii;
  }
}

// ---------------- per-tile segment partial sums (features resized on the fly) ----------------
__global__ __launch_bounds__(256) void k_segsum(const int* __restrict__ maskobj,
    const float* __restrict__ fsmall, float* __restrict__ psum, float* __restrict__ pcnt){
  int b = blockIdx.x; int n = b >> 8; int p0 = (b & 255) * 256;
  __shared__ float lsum[640];
  __shared__ float lcnt[32];
  for (int i = threadIdx.x; i < 640; i += 256) lsum[i] = 0.f;
  if (threadIdx.x < 32) lcnt[threadIdx.x] = 0.f;
  __syncthreads();
  int p = p0 + threadIdx.x;
  int id = maskobj[n * 65536 + p];
  atomicAdd(&lcnt[id], 1.f);
  int y = p >> 8, xo = p & 255;
  // bilinear upscale 16->256, half-pixel, edge-clamped
  float syf = (y + 0.5f) * 0.0625f - 0.5f; int sy0 = (int)floorf(syf); float fy = syf - sy0;
  int y0 = max(sy0, 0), y1i = min(sy0 + 1, 15);
  float sxf = (xo + 0.5f) * 0.0625f - 0.5f; int sx0 = (int)floorf(sxf); float fx = sxf - sx0;
  int x0 = max(sx0, 0), x1i = min(sx0 + 1, 15);
  const float* fs = fsmall + (size_t)n * 20 * 256;
  for (int c = 0; c < 20; c++){
    const float* F = fs + c * 256;
    float v = (1.f - fy) * ((1.f - fx) * F[y0 * 16 + x0] + fx * F[y0 * 16 + x1i])
            +        fy  * ((1.f - fx) * F[y1i * 16 + x0] + fx * F[y1i * 16 + x1i]);
    atomicAdd(&lsum[id * 20 + c], v);
  }
  __syncthreads();
  for (int i = threadIdx.x; i < 640; i += 256) psum[(size_t)b * 640 + i] = lsum[i];
  if (threadIdx.x < 32) pcnt[(size_t)b * 32 + threadIdx.x] = lcnt[threadIdx.x];
}

// ---------------- reduce partials -> sums/cnt ----------------
__global__ __launch_bounds__(256) void k_reduce(const float* __restrict__ psum,
    const float* __restrict__ pcnt, float* __restrict__ sums, float* __restrict__ cnt){
  int idx = blockIdx.x * 256 + threadIdx.x;   // < 5120
  int n = idx / 640, r = idx % 640;
  float s = 0.f;
  for (int b = 0; b < 256; b++) s += psum[((size_t)n * 256 + b) * 640 + r];
  sums[idx] = s;
  if (idx < 256){
    int n2 = idx >> 5, s2 = idx & 31;
    float c = 0.f;
    for (int b = 0; b < 256; b++) c += pcnt[((size_t)n2 * 256 + b) * 32 + s2];
    cnt[idx] = c;
  }
}

// ---------------- means + cls_fea ----------------
__global__ __launch_bounds__(256) void k_means(const float* __restrict__ sums,
    const float* __restrict__ cnt, float* __restrict__ means, float* __restrict__ cls_fea){
  __shared__ float lm[5120];
  __shared__ float lc[256];
  int s = threadIdx.x;
  lc[s] = cnt[s];
  float c = fmaxf(lc[s], 1.f);
  for (int ch = 0; ch < 20; ch++){
    float m = sums[s * 20 + ch] / c;
    lm[s * 20 + ch] = m;
    means[s * 20 + ch] = m;
  }
  __syncthreads();
  if (s < 160){
    int n = s / 20, ch = s % 20;
    float m = -3.4e38f;
    for (int seg = 0; seg < 32; seg++){
      int g = n * 32 + seg;
      if (lc[g] > 0.f) m = fmaxf(m, lm[g * 20 + ch]);
    }
    cls_fea[s] = m;
  }
}

// ---------------- scatter means -> features output ----------------
__global__ __launch_bounds__(256) void k_scatter(const int* __restrict__ maskobj,
    const float* __restrict__ means, float* __restrict__ feat_out){
  int idx = blockIdx.x * 256 + threadIdx.x;   // 8*65536
  int n = idx >> 16, p = idx & 65535;
  int id = maskobj[idx];
  const float* mrow = means + (n * 32 + id) * 20;
  #pragma unroll
  for (int c = 0; c < 20; c++)
    feat_out[((size_t)n * 20 + c) * 65536 + p] = mrow[c];
}

extern "C" void kernel_launch(void* const* d_in, const int* in_sizes, int n_in,
                              void* d_out, int out_size, void* d_ws, size_t ws_size,
                              hipStream_t stream) {
  const float* x   = (const float*)d_in[0];
  const float* x4  = (const float*)d_in[1];
  const float* Wc  = (const float*)d_in[2];
  const float* W1  = (const float*)d_in[3];
  const float* b1  = (const float*)d_in[4];
  const float* g1  = (const float*)d_in[5];
  const float* be1 = (const float*)d_in[6];
  const float* m1  = (const float*)d_in[7];
  const float* v1  = (const float*)d_in[8];
  const float* W2  = (const float*)d_in[9];
  const float* b2  = (const float*)d_in[10];
  const float* g2  = (const float*)d_in[11];
  const float* be2 = (const float*)d_in[12];
  const float* m2  = (const float*)d_in[13];
  const float* v2  = (const float*)d_in[14];
  const float* W3  = (const float*)d_in[15];
  const float* b3  = (const float*)d_in[16];
  const float* g3  = (const float*)d_in[17];
  const float* be3 = (const float*)d_in[18];
  const float* m3  = (const float*)d_in[19];
  const float* v3  = (const float*)d_in[20];

  float* out = (float*)d_out;
  float* cls_out  = out;                 // [8,20]
  float* clsf_out = out + 160;           // [8,20]
  float* feat_out = out + 320;           // [8,20,256,256]
  float* mask_out = out + 320 + 10485760; // [8,32,256,256]

  float* wsf = (float*)d_ws;
  float* xs      = wsf;                          // 1,572,864
  float* fsmall  = wsf + 1572864;                // 40,960
  float* y1      = wsf + 1613824;                // 52,428,800
  int*   maskobj = (int*)(wsf + 54042624);       // 524,288
  float* psum    = wsf + 54566912;               // 1,310,720
  float* pcnt    = wsf + 55877632;               // 65,536
  float* sums    = wsf + 55943168;               // 5,120
  float* cnt     = wsf + 55948288;               // 256
  float* means   = wsf + 55948544;               // 5,120

  k_classifier<<<160, 256, 0, stream>>>(x4, Wc, fsmall, cls_out);
  k_resize_x<<<6144, 256, 0, stream>>>(x, xs);
  k_conv1<<<dim3(16, 16, 8), 256, 0, stream>>>(xs, W1, b1, g1, be1, m1, v1, y1);
  k_conv2<<<dim3(32, 32, 8), 256, 0, stream>>>(y1, W2, b2, g2, be2, m2, v2,
                                               W3, b3, g3, be3, m3, v3,
                                               mask_out, maskobj);
  k_segsum<<<2048, 256, 0, stream>>>(maskobj, fsmall, psum, pcnt);
  k_reduce<<<20, 256, 0, stream>>>(psum, pcnt, sums, cnt);
  k_means<<<1, 256, 0, stream>>>(sums, cnt, means, clsf_out);
  k_scatter<<<2048, 256, 0, stream>>>(maskobj, means, feat_out);
}

// Round 4
// 2078.577 us; speedup vs baseline: 1.6799x; 1.2347x over previous
//
#include <hip/hip_runtime.h>

#define BN_EPS 1e-5f

typedef float floatx4 __attribute__((ext_vector_type(4)));
typedef _Float16 half8 __attribute__((ext_vector_type(8)));
typedef _Float16 f16;

__device__ __forceinline__ void load16_lds(const void* gsrc, void* lds){
  __builtin_amdgcn_global_load_lds((const __attribute__((address_space(1))) unsigned int*)gsrc,
                                   (__attribute__((address_space(3))) unsigned int*)lds, 16, 0, 0);
}

// ---------------- prep: pack W2/W3 as scaled (x256) hi/lo f16 records + BN consts ----------------
// W2p record per (o9, oc): 208 f16 = [c0:hi32|lo32][c1][c2][c3: g0=[hi4,lo4] g1=[hi4,0x4]]
// W3p: [32 od][4 c][hi32|lo32] = 8192 f16
__global__ __launch_bounds__(256) void k_prep(
    const float* __restrict__ W2, const float* __restrict__ W3, const float* __restrict__ b3,
    const float* __restrict__ g1, const float* __restrict__ be1, const float* __restrict__ m1, const float* __restrict__ v1,
    const float* __restrict__ g2, const float* __restrict__ be2, const float* __restrict__ m2, const float* __restrict__ v2,
    const float* __restrict__ g3, const float* __restrict__ be3, const float* __restrict__ m3, const float* __restrict__ v3,
    f16* __restrict__ W2p, f16* __restrict__ W3p,
    float* __restrict__ s1, float* __restrict__ c1, float* __restrict__ s2, float* __restrict__ c2,
    float* __restrict__ s3p, float* __restrict__ c3p){
  int idx = blockIdx.x * 256 + threadIdx.x;
  if (idx < 209664){
    int r = idx / 208, t = idx % 208;
    int oc = r % 112, o9 = r / 112;
    int ky = o9 / 3, kx = o9 % 3;
    f16 outv;
    if (t < 192){
      int c = t >> 6, u = t & 63, hl = u >> 5, j = u & 31;
      int ic = c * 32 + j;
      float v = (oc < 100) ? W2[(oc * 100 + ic) * 9 + ky * 3 + kx] * 256.f : 0.f;
      f16 h = (f16)v;
      outv = hl ? (f16)(v - (float)h) : h;
    } else {
      int tt = t - 192, g = tt >> 3, e = tt & 7;
      int ic = 96 + (e & 3);
      float v = (oc < 100) ? W2[(oc * 100 + ic) * 9 + ky * 3 + kx] * 256.f : 0.f;
      f16 h = (f16)v;
      f16 l = (f16)(v - (float)h);
      if (g == 0) outv = (e < 4) ? h : l;        // [hi4, lo4]
      else        outv = (e < 4) ? h : (f16)0.f; // [hi4, 0]
    }
    W2p[idx] = outv;
  } else if (idx < 209664 + 8192){
    int j = idx - 209664;
    int od = j >> 8, t = j & 255;
    int c = t >> 6, u = t & 63, hl = u >> 5, jj = u & 31;
    int oc = c * 32 + jj;
    float v = (oc < 100) ? W3[od * 100 + oc] * 256.f : 0.f;
    f16 h = (f16)v;
    W3p[j] = hl ? (f16)(v - (float)h) : h;
  } else if (idx < 209664 + 8192 + 256){
    int j = idx - 209664 - 8192;
    if (j < 100){ float s = g1[j] * rsqrtf(v1[j] + BN_EPS); s1[j] = s; c1[j] = be1[j] - m1[j] * s; }
    else if (j < 200){ int t = j - 100; float s = g2[t] * rsqrtf(v2[t] + BN_EPS); s2[t] = s; c2[t] = be2[t] - m2[t] * s; }
    else if (j < 232){ int t = j - 200; float s = g3[t] * rsqrtf(v3[t] + BN_EPS); s3p[t] = s; c3p[t] = (b3[t] - m3[t]) * s + be3[t]; }
  }
}

// ---------------- classifier 1x1 conv + spatial max (cls) ----------------
__global__ __launch_bounds__(256) void k_classifier(const float* __restrict__ x4,
    const float* __restrict__ Wc, float* __restrict__ fsmall, float* __restrict__ cls){
  int nc = blockIdx.x; int n = nc / 20, c = nc % 20;
  __shared__ float wc[512];
  for (int k = threadIdx.x; k < 512; k += 256) wc[k] = Wc[c * 512 + k];
  __syncthreads();
  int p = threadIdx.x;
  const float* xp = x4 + (size_t)n * 512 * 256 + p;
  float acc = 0.f;
  #pragma unroll 8
  for (int k = 0; k < 512; k++) acc = fmaf(xp[(size_t)k * 256], wc[k], acc);
  fsmall[((size_t)n * 20 + c) * 256 + p] = acc;
  float m = acc;
  for (int off = 32; off > 0; off >>= 1) m = fmaxf(m, __shfl_down(m, off, 64));
  __shared__ float wmax[4];
  if ((threadIdx.x & 63) == 0) wmax[threadIdx.x >> 6] = m;
  __syncthreads();
  if (threadIdx.x == 0)
    cls[n * 20 + c] = fmaxf(fmaxf(wmax[0], wmax[1]), fmaxf(wmax[2], wmax[3]));
}

// ---------------- conv1 3x3 (3->100) + ReLU + BN1 -> y1 records (fused 4-tap resize of x) -------
// y1 pixel record: 208 f16 = [c0:hi32|lo32][c1][c2][c3: g0=[hi4,hi4] g1=[lo4,0x4]], values x256
__global__ __launch_bounds__(256) void k_conv1(const float* __restrict__ x,
    const float* __restrict__ W1, const float* __restrict__ b1,
    const float* __restrict__ s1, const float* __restrict__ c1,
    f16* __restrict__ y1){
  int n = blockIdx.z; int ty0 = blockIdx.y * 16, tx0 = blockIdx.x * 16;
  __shared__ float tile[3][18][19];
  const float w4[4] = {0.125f, 0.375f, 0.375f, 0.125f};
  for (int i = threadIdx.x; i < 972; i += 256){
    int ch = i / 324, r = i % 324;
    int yy = ty0 + r / 18 - 1, xx = tx0 + r % 18 - 1;
    float val = 0.f;
    if (yy >= 0 && yy < 256 && xx >= 0 && xx < 256){
      const float* src = x + (size_t)(n * 3 + ch) * 262144;
      float acc = 0.f, ws = 0.f;
      #pragma unroll
      for (int ty = 0; ty < 4; ty++){
        int sy = 2 * yy - 1 + ty; if (sy < 0 || sy > 511) continue;
        #pragma unroll
        for (int tx = 0; tx < 4; tx++){
          int sx = 2 * xx - 1 + tx; if (sx < 0 || sx > 511) continue;
          float w = w4[ty] * w4[tx];
          acc += w * src[sy * 512 + sx]; ws += w;
        }
      }
      val = acc / ws;
    }
    tile[ch][r / 18][r % 18] = val;
  }
  __syncthreads();
  int ly = threadIdx.x >> 4, lx = threadIdx.x & 15;
  float in[3][9];
  #pragma unroll
  for (int ch = 0; ch < 3; ch++)
    #pragma unroll
    for (int k = 0; k < 9; k++) in[ch][k] = tile[ch][ly + k / 3][lx + k % 3];
  f16* row = y1 + (size_t)((n * 256 + ty0 + ly) * 256 + tx0 + lx) * 208;
  for (int c = 0; c < 3; c++){
    float acc[32];
    #pragma unroll
    for (int o = 0; o < 32; o++) acc[o] = 0.f;
    #pragma unroll
    for (int ch = 0; ch < 3; ch++)
      #pragma unroll
      for (int o = 0; o < 32; o++)
        #pragma unroll
        for (int k = 0; k < 9; k++)
          acc[o] = fmaf(in[ch][k], W1[((c * 32 + o) * 3 + ch) * 9 + k], acc[o]);
    #pragma unroll
    for (int g = 0; g < 4; g++){
      half8 hv, lv;
      #pragma unroll
      for (int e = 0; e < 8; e++){
        int j = g * 8 + e, oc = c * 32 + j;
        float v = (fmaxf(acc[j] + b1[oc], 0.f) * s1[oc] + c1[oc]) * 256.f;
        f16 h = (f16)v;
        hv[e] = h; lv[e] = (f16)(v - (float)h);
      }
      *(half8*)(row + c * 64 + g * 8) = hv;
      *(half8*)(row + c * 64 + 32 + g * 8) = lv;
    }
  }
  float a3[4];
  #pragma unroll
  for (int o = 0; o < 4; o++) a3[o] = 0.f;
  #pragma unroll
  for (int ch = 0; ch < 3; ch++)
    #pragma unroll
    for (int o = 0; o < 4; o++)
      #pragma unroll
      for (int k = 0; k < 9; k++)
        a3[o] = fmaf(in[ch][k], W1[((96 + o) * 3 + ch) * 9 + k], a3[o]);
  half8 g0, g1v;
  #pragma unroll
  for (int e = 0; e < 8; e++){
    int oc = 96 + (e & 3);
    float v = (fmaxf(a3[e & 3] + b1[oc], 0.f) * s1[oc] + c1[oc]) * 256.f;
    f16 h = (f16)v;
    g0[e] = h;
    g1v[e] = (e < 4) ? (f16)(v - (float)h) : (f16)0.f;
  }
  *(half8*)(row + 192) = g0;
  *(half8*)(row + 200) = g1v;
}

// ---------------- conv2 3x3 (100->100) split-f16 MFMA + BN2 + conv3(1x1,split) + BN3 + argmax ----
__global__ __launch_bounds__(256, 2) void k_conv2(const f16* __restrict__ y1,
    const f16* __restrict__ W2p, const f16* __restrict__ W3p,
    const float* __restrict__ b2, const float* __restrict__ s2, const float* __restrict__ c2,
    const float* __restrict__ s3p, const float* __restrict__ c3p,
    const float* __restrict__ zpage,
    float* __restrict__ mask_out, int* __restrict__ maskobj){
  __shared__ __align__(16) char smem[76288];   // A: 260 slots x 128B; B at +33280: 336 slots x 128B
  int n = blockIdx.y;
  int bid = blockIdx.x;
  int row = ((bid & 7) << 5) + ((bid >> 3) & 31);   // L2-locality swizzle: 32-row bands
  int lane = threadIdx.x & 63;
  int wvu = __builtin_amdgcn_readfirstlane(threadIdx.x >> 6);
  int l15 = lane & 15, quad = lane >> 4;

  floatx4 acc[4][7];
  #pragma unroll
  for (int mt = 0; mt < 4; mt++)
    #pragma unroll
    for (int nt = 0; nt < 7; nt++) acc[mt][nt] = {0.f, 0.f, 0.f, 0.f};

  const f16* yn = y1 + (size_t)n * 65536 * 208;
  for (int c = 0; c < 4; c++){
    bool lastc = (c == 3);
    for (int ky = 0; ky < 3; ky++){
      __syncthreads();
      int yy = row + ky - 1;
      bool rowOOB = (yy < 0) || (yy > 255);
      const f16* rb = yn + (size_t)yy * (256 * 208) + (lastc ? 192 : c * 64);
      // ---- stage A: 2080 granules (260 slots x 8), XOR-swizzled ----
      #pragma unroll
      for (int it = 0; it < 8; it++){
        int G = it * 256 + threadIdx.x;
        int s = G >> 3, p = G & 7, q = p ^ (s & 7);
        int xx = s - 1;
        bool ok = !rowOOB && ((unsigned)xx < 256u) && (!lastc || q < 2);
        const f16* src = ok ? (rb + (size_t)xx * 208 + q * 8) : (const f16*)zpage;
        load16_lds(src, smem + (size_t)(it * 256 + wvu * 64) * 16);
      }
      if (threadIdx.x < 32){
        int G = 2048 + threadIdx.x;
        int s = G >> 3, p = G & 7, q = p ^ (s & 7);
        int xx = s - 1;
        bool ok = !rowOOB && ((unsigned)xx < 256u) && (!lastc || q < 2);
        const f16* src = ok ? (rb + (size_t)xx * 208 + q * 8) : (const f16*)zpage;
        load16_lds(src, smem + (size_t)2048 * 16);
      }
      // ---- stage B: 2688 granules (336 slots x 8): slot s -> record (ky*336 + s) ----
      #pragma unroll
      for (int it = 0; it < 10; it++){
        int G = it * 256 + threadIdx.x;
        int s = G >> 3, p = G & 7, q = p ^ (s & 7);
        bool ok = (!lastc || q < 2);
        const f16* src = ok ? (W2p + (size_t)(ky * 336 + s) * 208 + (lastc ? 192 : c * 64) + q * 8)
                            : (const f16*)zpage;
        load16_lds(src, smem + 33280 + (size_t)(it * 256 + wvu * 64) * 16);
      }
      if (threadIdx.x < 128){
        int G = 2560 + threadIdx.x;
        int s = G >> 3, p = G & 7, q = p ^ (s & 7);
        bool ok = (!lastc || q < 2);
        const f16* src = ok ? (W2p + (size_t)(ky * 336 + s) * 208 + (lastc ? 192 : c * 64) + q * 8)
                            : (const f16*)zpage;
        load16_lds(src, smem + 33280 + (size_t)(2560 + wvu * 64) * 16);
      }
      __syncthreads();
      // ---- compute ----
      if (!lastc){
        #pragma unroll
        for (int kx = 0; kx < 3; kx++){
          half8 bh[7], bl[7];
          #pragma unroll
          for (int nt = 0; nt < 7; nt++){
            int bs = kx * 112 + nt * 16 + l15;
            const char* bp = smem + 33280 + bs * 128;
            bh[nt] = *(const half8*)(bp + ((quad ^ (bs & 7)) << 4));
            bl[nt] = *(const half8*)(bp + (((quad + 4) ^ (bs & 7)) << 4));
          }
          #pragma unroll
          for (int mt = 0; mt < 4; mt++){
            int as = (wvu * 4 + mt) * 16 + l15 + kx;
            const char* ap = smem + as * 128;
            half8 ah = *(const half8*)(ap + ((quad ^ (as & 7)) << 4));
            half8 al = *(const half8*)(ap + (((quad + 4) ^ (as & 7)) << 4));
            #pragma unroll
            for (int nt = 0; nt < 7; nt++){
              acc[mt][nt] = __builtin_amdgcn_mfma_f32_16x16x32_f16(ah, bh[nt], acc[mt][nt], 0, 0, 0);
              acc[mt][nt] = __builtin_amdgcn_mfma_f32_16x16x32_f16(ah, bl[nt], acc[mt][nt], 0, 0, 0);
              acc[mt][nt] = __builtin_amdgcn_mfma_f32_16x16x32_f16(al, bh[nt], acc[mt][nt], 0, 0, 0);
            }
          }
        }
      } else {
        // ic 96..99 packed K: A=[hi4,hi4][lo4,0], B=[hi4,lo4][hi4,0] -> all 3 products in one MFMA
        #pragma unroll
        for (int kx = 0; kx < 3; kx++){
          half8 bh[7];
          #pragma unroll
          for (int nt = 0; nt < 7; nt++){
            int bs = kx * 112 + nt * 16 + l15;
            bh[nt] = *(const half8*)(smem + 33280 + bs * 128 + ((quad ^ (bs & 7)) << 4));
          }
          #pragma unroll
          for (int mt = 0; mt < 4; mt++){
            int as = (wvu * 4 + mt) * 16 + l15 + kx;
            half8 ah = *(const half8*)(smem + as * 128 + ((quad ^ (as & 7)) << 4));
            #pragma unroll
            for (int nt = 0; nt < 7; nt++)
              acc[mt][nt] = __builtin_amdgcn_mfma_f32_16x16x32_f16(ah, bh[nt], acc[mt][nt], 0, 0, 0);
          }
        }
      }
    }
  }

  // ---------------- epilogue ----------------
  __syncthreads();
  f16* y2 = (f16*)(smem + wvu * 16896);   // per-wave [32 px][264 f16]: hi 0..127, lo 128..255, pad
  half8 w3h[2][4], w3l[2][4];
  #pragma unroll
  for (int odt = 0; odt < 2; odt++)
    #pragma unroll
    for (int ks = 0; ks < 4; ks++){
      const f16* wp = W3p + ((odt * 16 + l15) * 4 + ks) * 64 + quad * 8;
      w3h[odt][ks] = *(const half8*)wp;
      w3l[odt][ks] = *(const half8*)(wp + 32);
    }
  float b2v[7], s2v[7], c2v[7];
  #pragma unroll
  for (int nt = 0; nt < 7; nt++){
    int oc = min(nt * 16 + l15, 99);
    b2v[nt] = b2[oc]; s2v[nt] = s2[oc]; c2v[nt] = c2[oc];
  }
  const float inv = 1.52587890625e-05f;   // 2^-16
  float s3a = s3p[l15] * inv, c3a = c3p[l15];
  float s3b = s3p[l15 + 16] * inv, c3b = c3p[l15 + 16];

  float* mout = mask_out + (size_t)n * 32 * 65536 + (size_t)row * 256;
  int*   mobj = maskobj + (size_t)n * 65536 + (size_t)row * 256;

  for (int pass = 0; pass < 2; pass++){
    if (lane < 32){
      floatx4 z = {0.f, 0.f, 0.f, 0.f};
      *(floatx4*)(y2 + lane * 264 + 112) = z;
      *(floatx4*)(y2 + lane * 264 + 120) = z;
      *(floatx4*)(y2 + lane * 264 + 240) = z;
      *(floatx4*)(y2 + lane * 264 + 248) = z;
    }
    #pragma unroll
    for (int mtp = 0; mtp < 2; mtp++){
      int mt = pass * 2 + mtp;
      #pragma unroll
      for (int nt = 0; nt < 7; nt++){
        #pragma unroll
        for (int r = 0; r < 4; r++){
          float yv = fmaxf(acc[mt][nt][r] * inv + b2v[nt], 0.f) * s2v[nt] + c2v[nt];
          float ys = yv * 256.f;
          f16 h = (f16)ys;
          int rr = mtp * 16 + quad * 4 + r;
          y2[rr * 264 + nt * 16 + l15] = h;
          y2[rr * 264 + 128 + nt * 16 + l15] = (f16)(ys - (float)h);
        }
      }
    }
    floatx4 macc[2][2];
    #pragma unroll
    for (int mtp = 0; mtp < 2; mtp++)
      #pragma unroll
      for (int odt = 0; odt < 2; odt++) macc[mtp][odt] = {0.f, 0.f, 0.f, 0.f};
    #pragma unroll
    for (int ks = 0; ks < 4; ks++){
      #pragma unroll
      for (int mtp = 0; mtp < 2; mtp++){
        const f16* ap = y2 + (mtp * 16 + l15) * 264 + ks * 32 + quad * 8;
        half8 ah = *(const half8*)ap;
        half8 al = *(const half8*)(ap + 128);
        #pragma unroll
        for (int odt = 0; odt < 2; odt++){
          macc[mtp][odt] = __builtin_amdgcn_mfma_f32_16x16x32_f16(ah, w3h[odt][ks], macc[mtp][odt], 0, 0, 0);
          macc[mtp][odt] = __builtin_amdgcn_mfma_f32_16x16x32_f16(ah, w3l[odt][ks], macc[mtp][odt], 0, 0, 0);
          macc[mtp][odt] = __builtin_amdgcn_mfma_f32_16x16x32_f16(al, w3h[odt][ks], macc[mtp][odt], 0, 0, 0);
        }
      }
    }
    #pragma unroll
    for (int mtp = 0; mtp < 2; mtp++){
      #pragma unroll
      for (int r = 0; r < 4; r++){
        float v0 = macc[mtp][0][r] * s3a + c3a;   // od = l15
        float v1 = macc[mtp][1][r] * s3b + c3b;   // od = l15+16
        int px = 64 * wvu + pass * 32 + mtp * 16 + quad * 4 + r;
        mout[(size_t)l15 * 65536 + px] = v0;
        mout[(size_t)(l15 + 16) * 65536 + px] = v1;
        float bv = v0; int bi = l15;
        if (v1 > bv){ bv = v1; bi = l15 + 16; }
        #pragma unroll
        for (int off = 1; off < 16; off <<= 1){
          float ov = __shfl_xor(bv, off, 16);
          int   oi = __shfl_xor(bi, off, 16);
          if (ov > bv || (ov == bv && oi < bi)){ bv = ov; bi = oi; }
        }
        if (l15 == 0) mobj[px] = bi;
      }
    }
    __syncthreads();
  }
}

// ---------------- per-tile segment partial sums (features resized on the fly) ----------------
__global__ __launch_bounds__(256) void k_segsum(const int* __restrict__ maskobj,
    const float* __restrict__ fsmall, float* __restrict__ psum, float* __restrict__ pcnt){
  int b = blockIdx.x; int n = b >> 8; int p0 = (b & 255) * 256;
  __shared__ float lsum[640];
  __shared__ float lcnt[32];
  for (int i = threadIdx.x; i < 640; i += 256) lsum[i] = 0.f;
  if (threadIdx.x < 32) lcnt[threadIdx.x] = 0.f;
  __syncthreads();
  int p = p0 + threadIdx.x;
  int id = maskobj[n * 65536 + p];
  atomicAdd(&lcnt[id], 1.f);
  int y = p >> 8, xo = p & 255;
  float syf = (y + 0.5f) * 0.0625f - 0.5f; int sy0 = (int)floorf(syf); float fy = syf - sy0;
  int y0 = max(sy0, 0), y1i = min(sy0 + 1, 15);
  float sxf = (xo + 0.5f) * 0.0625f - 0.5f; int sx0 = (int)floorf(sxf); float fx = sxf - sx0;
  int x0 = max(sx0, 0), x1i = min(sx0 + 1, 15);
  const float* fs = fsmall + (size_t)n * 20 * 256;
  for (int c = 0; c < 20; c++){
    const float* F = fs + c * 256;
    float v = (1.f - fy) * ((1.f - fx) * F[y0 * 16 + x0] + fx * F[y0 * 16 + x1i])
            +        fy  * ((1.f - fx) * F[y1i * 16 + x0] + fx * F[y1i * 16 + x1i]);
    atomicAdd(&lsum[id * 20 + c], v);
  }
  __syncthreads();
  for (int i = threadIdx.x; i < 640; i += 256) psum[(size_t)b * 640 + i] = lsum[i];
  if (threadIdx.x < 32) pcnt[(size_t)b * 32 + threadIdx.x] = lcnt[threadIdx.x];
}

// ---------------- reduce partials -> sums/cnt ----------------
__global__ __launch_bounds__(256) void k_reduce(const float* __restrict__ psum,
    const float* __restrict__ pcnt, float* __restrict__ sums, float* __restrict__ cnt){
  int idx = blockIdx.x * 256 + threadIdx.x;
  int n = idx / 640, r = idx % 640;
  float s = 0.f;
  for (int b = 0; b < 256; b++) s += psum[((size_t)n * 256 + b) * 640 + r];
  sums[idx] = s;
  if (idx < 256){
    int n2 = idx >> 5, s2 = idx & 31;
    float c = 0.f;
    for (int b = 0; b < 256; b++) c += pcnt[((size_t)n2 * 256 + b) * 32 + s2];
    cnt[idx] = c;
  }
}

// ---------------- means + cls_fea ----------------
__global__ __launch_bounds__(256) void k_means(const float* __restrict__ sums,
    const float* __restrict__ cnt, float* __restrict__ means, float* __restrict__ cls_fea){
  __shared__ float lm[5120];
  __shared__ float lc[256];
  int s = threadIdx.x;
  lc[s] = cnt[s];
  float c = fmaxf(lc[s], 1.f);
  for (int ch = 0; ch < 20; ch++){
    float m = sums[s * 20 + ch] / c;
    lm[s * 20 + ch] = m;
    means[s * 20 + ch] = m;
  }
  __syncthreads();
  if (s < 160){
    int n = s / 20, ch = s % 20;
    float m = -3.4e38f;
    for (int seg = 0; seg < 32; seg++){
      int g = n * 32 + seg;
      if (lc[g] > 0.f) m = fmaxf(m, lm[g * 20 + ch]);
    }
    cls_fea[s] = m;
  }
}

// ---------------- scatter means -> features output ----------------
__global__ __launch_bounds__(256) void k_scatter(const int* __restrict__ maskobj,
    const float* __restrict__ means, float* __restrict__ feat_out){
  int idx = blockIdx.x * 256 + threadIdx.x;
  int n = idx >> 16, p = idx & 65535;
  int id = maskobj[idx];
  const float* mrow = means + (n * 32 + id) * 20;
  #pragma unroll
  for (int c = 0; c < 20; c++)
    feat_out[((size_t)n * 20 + c) * 65536 + p] = mrow[c];
}

extern "C" void kernel_launch(void* const* d_in, const int* in_sizes, int n_in,
                              void* d_out, int out_size, void* d_ws, size_t ws_size,
                              hipStream_t stream) {
  const float* x   = (const float*)d_in[0];
  const float* x4  = (const float*)d_in[1];
  const float* Wc  = (const float*)d_in[2];
  const float* W1  = (const float*)d_in[3];
  const float* b1  = (const float*)d_in[4];
  const float* g1  = (const float*)d_in[5];
  const float* be1 = (const float*)d_in[6];
  const float* m1  = (const float*)d_in[7];
  const float* v1  = (const float*)d_in[8];
  const float* W2  = (const float*)d_in[9];
  const float* b2  = (const float*)d_in[10];
  const float* g2  = (const float*)d_in[11];
  const float* be2 = (const float*)d_in[12];
  const float* m2  = (const float*)d_in[13];
  const float* v2  = (const float*)d_in[14];
  const float* W3  = (const float*)d_in[15];
  const float* b3  = (const float*)d_in[16];
  const float* g3  = (const float*)d_in[17];
  const float* be3 = (const float*)d_in[18];
  const float* m3  = (const float*)d_in[19];
  const float* v3  = (const float*)d_in[20];

  float* out = (float*)d_out;
  float* cls_out  = out;                  // [8,20]
  float* clsf_out = out + 160;            // [8,20]
  float* feat_out = out + 320;            // [8,20,256,256]
  float* mask_out = out + 320 + 10485760; // [8,32,256,256]

  float* wsf = (float*)d_ws;
  float* fsmall  = wsf;                          // 40,960 f32
  int*   maskobj = (int*)(wsf + 40960);          // 524,288 int
  float* pcnt    = wsf + 565248;                 // 65,536 f32
  float* sums    = wsf + 630784;                 // 5,120
  float* cnt     = wsf + 635904;                 // 256
  float* means   = wsf + 636160;                 // 5,120
  f16*   W2p     = (f16*)(wsf + 641280);         // 209,664 f16
  f16*   W3p     = (f16*)(wsf + 746112);         // 8,192 f16
  float* s1      = wsf + 750208;  float* c1 = s1 + 100;
  float* s2      = c1 + 100;      float* c2 = s2 + 100;
  float* s3p     = c2 + 100;      float* c3p = s3p + 32;
  float* zpage   = wsf + 750720;                 // 64 f32 zeros (16B aligned)
  f16*   y1f     = (f16*)(wsf + 750848);         // 109,051,904 f16 = 218.1 MB
  float* psum    = (float*)y1f;                  // overlay: y1 dead before segsum

  hipMemsetAsync(zpage, 0, 256, stream);
  k_prep<<<852, 256, 0, stream>>>(W2, W3, b3, g1, be1, m1, v1, g2, be2, m2, v2,
                                  g3, be3, m3, v3, W2p, W3p, s1, c1, s2, c2, s3p, c3p);
  k_classifier<<<160, 256, 0, stream>>>(x4, Wc, fsmall, cls_out);
  k_conv1<<<dim3(16, 16, 8), 256, 0, stream>>>(x, W1, b1, s1, c1, y1f);
  k_conv2<<<dim3(256, 8), 256, 0, stream>>>(y1f, W2p, W3p, b2, s2, c2, s3p, c3p,
                                            zpage, mask_out, maskobj);
  k_segsum<<<2048, 256, 0, stream>>>(maskobj, fsmall, psum, pcnt);
  k_reduce<<<20, 256, 0, stream>>>(psum, pcnt, sums, cnt);
  k_means<<<1, 256, 0, stream>>>(sums, cnt, means, clsf_out);
  k_scatter<<<2048, 256, 0, stream>>>(maskobj, means, feat_out);
}

// Round 5
// 2034.097 us; speedup vs baseline: 1.7167x; 1.0219x over previous
//
#include <hip/hip_runtime.h>

#define BN_EPS 1e-5f

typedef float floatx4 __attribute__((ext_vector_type(4)));
typedef int   intx4   __attribute__((ext_vector_type(4)));
typedef _Float16 half8 __attribute__((ext_vector_type(8)));
typedef _Float16 f16;

__device__ __forceinline__ void load16_lds(const void* gsrc, void* lds){
  __builtin_amdgcn_global_load_lds((const __attribute__((address_space(1))) unsigned int*)gsrc,
                                   (__attribute__((address_space(3))) unsigned int*)lds, 16, 0, 0);
}

// ---------------- prep: planar packed weights (x256 hi/lo f16) + BN consts ----------------
// W2a: [c(3)][ky(3)][kx(3)][oc(112)][hi32|lo32]           = 193,536 f16
// W2c3:[ky(3)][kx(3)][oc(112)][g0:hi4,lo4 | g1:hi4,0x4]   =  16,128 f16
// W3p: [od(32)][c(4)][hi32|lo32]                          =   8,192 f16
__global__ __launch_bounds__(256) void k_prep(
    const float* __restrict__ W2, const float* __restrict__ W3, const float* __restrict__ b3,
    const float* __restrict__ g1, const float* __restrict__ be1, const float* __restrict__ m1, const float* __restrict__ v1,
    const float* __restrict__ g2, const float* __restrict__ be2, const float* __restrict__ m2, const float* __restrict__ v2,
    const float* __restrict__ g3, const float* __restrict__ be3, const float* __restrict__ m3, const float* __restrict__ v3,
    f16* __restrict__ W2a, f16* __restrict__ W2c3, f16* __restrict__ W3p,
    float* __restrict__ s1, float* __restrict__ c1, float* __restrict__ s2, float* __restrict__ c2,
    float* __restrict__ s3p, float* __restrict__ c3p){
  int idx = blockIdx.x * 256 + threadIdx.x;
  if (idx < 193536){
    int e = idx & 63; int s6 = idx >> 6;             // s6 < 3024
    int oc = s6 % 112, k9 = (s6 / 112) % 9, c = s6 / 1008;
    int hl = e >> 5, j = e & 31, ic = c * 32 + j;
    float v = (oc < 100) ? W2[(oc * 100 + ic) * 9 + k9] * 256.f : 0.f;
    f16 h = (f16)v;
    W2a[idx] = hl ? (f16)(v - (float)h) : h;
  } else if (idx < 193536 + 16128){
    int t = idx - 193536;
    int e = t & 15; int s4 = t >> 4;                 // s4 < 1008
    int oc = s4 % 112, k9 = s4 / 112;
    int g = e >> 3, ee = e & 7, ic = 96 + (ee & 3);
    float v = (oc < 100) ? W2[(oc * 100 + ic) * 9 + k9] * 256.f : 0.f;
    f16 h = (f16)v;
    f16 l = (f16)(v - (float)h);
    f16 outv;
    if (g == 0) outv = (ee < 4) ? h : l;
    else        outv = (ee < 4) ? h : (f16)0.f;
    W2c3[t] = outv;
  } else if (idx < 193536 + 16128 + 8192){
    int j = idx - 193536 - 16128;
    int od = j >> 8, t = j & 255;
    int c = t >> 6, u = t & 63, hl = u >> 5, jj = u & 31;
    int oc = c * 32 + jj;
    float v = (oc < 100) ? W3[od * 100 + oc] * 256.f : 0.f;
    f16 h = (f16)v;
    W3p[j] = hl ? (f16)(v - (float)h) : h;
  } else if (idx < 193536 + 16128 + 8192 + 256){
    int j = idx - 193536 - 16128 - 8192;
    if (j < 100){ float s = g1[j] * rsqrtf(v1[j] + BN_EPS); s1[j] = s; c1[j] = be1[j] - m1[j] * s; }
    else if (j < 200){ int t = j - 100; float s = g2[t] * rsqrtf(v2[t] + BN_EPS); s2[t] = s; c2[t] = be2[t] - m2[t] * s; }
    else if (j < 232){ int t = j - 200; float s = g3[t] * rsqrtf(v3[t] + BN_EPS); s3p[t] = s; c3p[t] = (b3[t] - m3[t]) * s + be3[t]; }
  }
}

// ---------------- classifier 1x1 conv + spatial max (cls) ----------------
__global__ __launch_bounds__(256) void k_classifier(const float* __restrict__ x4,
    const float* __restrict__ Wc, float* __restrict__ fsmall, float* __restrict__ cls){
  int nc = blockIdx.x; int n = nc / 20, c = nc % 20;
  __shared__ float wc[512];
  for (int k = threadIdx.x; k < 512; k += 256) wc[k] = Wc[c * 512 + k];
  __syncthreads();
  int p = threadIdx.x;
  const float* xp = x4 + (size_t)n * 512 * 256 + p;
  float acc = 0.f;
  #pragma unroll 8
  for (int k = 0; k < 512; k++) acc = fmaf(xp[(size_t)k * 256], wc[k], acc);
  fsmall[((size_t)n * 20 + c) * 256 + p] = acc;
  float m = acc;
  for (int off = 32; off > 0; off >>= 1) m = fmaxf(m, __shfl_down(m, off, 64));
  __shared__ float wmax[4];
  if ((threadIdx.x & 63) == 0) wmax[threadIdx.x >> 6] = m;
  __syncthreads();
  if (threadIdx.x == 0)
    cls[n * 20 + c] = fmaxf(fmaxf(wmax[0], wmax[1]), fmaxf(wmax[2], wmax[3]));
}

// ---------------- conv1 3x3 (3->100) + ReLU + BN1 -> y1 planar hi/lo f16 (x256), fused resize ----
// y1a plane (c<3): [n][c][p][hi32|lo32];  y1c3: [n][p][g0:hi4,hi4 | g1:lo4,0x4]
__global__ __launch_bounds__(256) void k_conv1(const float* __restrict__ x,
    const float* __restrict__ W1, const float* __restrict__ b1,
    const float* __restrict__ s1, const float* __restrict__ c1,
    f16* __restrict__ y1a, f16* __restrict__ y1c3){
  int n = blockIdx.z; int ty0 = blockIdx.y * 16, tx0 = blockIdx.x * 16;
  __shared__ float tile[3][18][19];
  const float w4[4] = {0.125f, 0.375f, 0.375f, 0.125f};
  for (int i = threadIdx.x; i < 972; i += 256){
    int ch = i / 324, r = i % 324;
    int yy = ty0 + r / 18 - 1, xx = tx0 + r % 18 - 1;
    float val = 0.f;
    if (yy >= 0 && yy < 256 && xx >= 0 && xx < 256){
      const float* src = x + (size_t)(n * 3 + ch) * 262144;
      float acc = 0.f, ws = 0.f;
      #pragma unroll
      for (int ty = 0; ty < 4; ty++){
        int sy = 2 * yy - 1 + ty; if (sy < 0 || sy > 511) continue;
        #pragma unroll
        for (int tx = 0; tx < 4; tx++){
          int sx = 2 * xx - 1 + tx; if (sx < 0 || sx > 511) continue;
          float w = w4[ty] * w4[tx];
          acc += w * src[sy * 512 + sx]; ws += w;
        }
      }
      val = acc / ws;
    }
    tile[ch][r / 18][r % 18] = val;
  }
  __syncthreads();
  int ly = threadIdx.x >> 4, lx = threadIdx.x & 15;
  float in[3][9];
  #pragma unroll
  for (int ch = 0; ch < 3; ch++)
    #pragma unroll
    for (int k = 0; k < 9; k++) in[ch][k] = tile[ch][ly + k / 3][lx + k % 3];
  int p = (ty0 + ly) * 256 + tx0 + lx;
  for (int c = 0; c < 3; c++){
    float acc[32];
    #pragma unroll
    for (int o = 0; o < 32; o++) acc[o] = 0.f;
    #pragma unroll
    for (int ch = 0; ch < 3; ch++)
      #pragma unroll
      for (int o = 0; o < 32; o++)
        #pragma unroll
        for (int k = 0; k < 9; k++)
          acc[o] = fmaf(in[ch][k], W1[((c * 32 + o) * 3 + ch) * 9 + k], acc[o]);
    f16* rec = y1a + ((size_t)(n * 3 + c) * 65536 + p) * 64;
    #pragma unroll
    for (int g = 0; g < 4; g++){
      half8 hv, lv;
      #pragma unroll
      for (int e = 0; e < 8; e++){
        int j = g * 8 + e, oc = c * 32 + j;
        float v = (fmaxf(acc[j] + b1[oc], 0.f) * s1[oc] + c1[oc]) * 256.f;
        f16 h = (f16)v;
        hv[e] = h; lv[e] = (f16)(v - (float)h);
      }
      *(half8*)(rec + g * 8) = hv;
      *(half8*)(rec + 32 + g * 8) = lv;
    }
  }
  float a3[4];
  #pragma unroll
  for (int o = 0; o < 4; o++) a3[o] = 0.f;
  #pragma unroll
  for (int ch = 0; ch < 3; ch++)
    #pragma unroll
    for (int o = 0; o < 4; o++)
      #pragma unroll
      for (int k = 0; k < 9; k++)
        a3[o] = fmaf(in[ch][k], W1[((96 + o) * 3 + ch) * 9 + k], a3[o]);
  half8 g0, g1v;
  #pragma unroll
  for (int e = 0; e < 8; e++){
    int oc = 96 + (e & 3);
    float v = (fmaxf(a3[e & 3] + b1[oc], 0.f) * s1[oc] + c1[oc]) * 256.f;
    f16 h = (f16)v;
    g0[e] = h;
    g1v[e] = (e < 4) ? (f16)(v - (float)h) : (f16)0.f;
  }
  f16* rec3 = y1c3 + ((size_t)n * 65536 + p) * 16;
  *(half8*)(rec3) = g0;
  *(half8*)(rec3 + 8) = g1v;
}

// ---------------- conv2 3x3 (100->100) split-f16 MFMA + BN2 + conv3(1x1,split) + BN3 + argmax ----
__global__ __launch_bounds__(256, 2) void k_conv2(
    const f16* __restrict__ y1a, const f16* __restrict__ y1c3,
    const f16* __restrict__ W2a, const f16* __restrict__ W2c3, const f16* __restrict__ W3p,
    const float* __restrict__ b2, const float* __restrict__ s2, const float* __restrict__ c2,
    const float* __restrict__ s3p, const float* __restrict__ c3p,
    const float* __restrict__ zpage,
    float* __restrict__ mask_out, int* __restrict__ maskobj){
  __shared__ __align__(16) char smem[76288];   // A: 260 slots x 128B; B at +33280: 336 slots x 128B
  int n = blockIdx.y;
  int bid = blockIdx.x;
  int row = ((bid & 7) << 5) + ((bid >> 3) & 31);   // 32-row bands per XCD for halo L2 reuse
  int lane = threadIdx.x & 63;
  int wvu = __builtin_amdgcn_readfirstlane(threadIdx.x >> 6);
  int l15 = lane & 15, quad = lane >> 4;

  floatx4 acc[4][7];
  #pragma unroll
  for (int mt = 0; mt < 4; mt++)
    #pragma unroll
    for (int nt = 0; nt < 7; nt++) acc[mt][nt] = {0.f, 0.f, 0.f, 0.f};

  for (int c = 0; c < 4; c++){
    bool lastc = (c == 3);
    for (int ky = 0; ky < 3; ky++){
      __syncthreads();
      int yy = row + ky - 1;
      bool rowOOB = (yy < 0) || (yy > 255);
      const f16* rb  = y1a + ((size_t)(n * 3 + c) * 65536 + (size_t)yy * 256) * 64;
      const f16* rb3 = y1c3 + ((size_t)n * 65536 + (size_t)yy * 256) * 16;
      // ---- stage A: 260 slots x 8 granules, fully contiguous source ----
      #pragma unroll
      for (int it = 0; it < 8; it++){
        int G = it * 256 + threadIdx.x;
        int s = G >> 3, p = G & 7, q = p ^ (s & 7);
        int xx = s - 1;
        const f16* src;
        if (rowOOB || (unsigned)xx >= 256u) src = (const f16*)zpage;
        else if (!lastc)                    src = rb + (size_t)xx * 64 + q * 8;
        else                                src = (q < 2) ? (rb3 + (size_t)xx * 16 + q * 8) : (const f16*)zpage;
        load16_lds(src, smem + (size_t)(it * 256 + wvu * 64) * 16);
      }
      if (threadIdx.x < 32){
        int G = 2048 + threadIdx.x;
        int s = G >> 3, p = G & 7, q = p ^ (s & 7);
        int xx = s - 1;
        const f16* src;
        if (rowOOB || (unsigned)xx >= 256u) src = (const f16*)zpage;
        else if (!lastc)                    src = rb + (size_t)xx * 64 + q * 8;
        else                                src = (q < 2) ? (rb3 + (size_t)xx * 16 + q * 8) : (const f16*)zpage;
        load16_lds(src, smem + (size_t)2048 * 16);
      }
      // ---- stage B: 336 slots (kx*112+oc) x 8 granules, contiguous source ----
      const f16* wb  = W2a + (size_t)(c * 9 + ky * 3) * 112 * 64;
      const f16* wb3 = W2c3 + (size_t)(ky * 3) * 112 * 16;
      #pragma unroll
      for (int it = 0; it < 10; it++){
        int G = it * 256 + threadIdx.x;
        int s = G >> 3, p = G & 7, q = p ^ (s & 7);
        const f16* src;
        if (!lastc) src = wb + (size_t)s * 64 + q * 8;
        else        src = (q < 2) ? (wb3 + (size_t)s * 16 + q * 8) : (const f16*)zpage;
        load16_lds(src, smem + 33280 + (size_t)(it * 256 + wvu * 64) * 16);
      }
      if (threadIdx.x < 128){
        int G = 2560 + threadIdx.x;
        int s = G >> 3, p = G & 7, q = p ^ (s & 7);
        const f16* src;
        if (!lastc) src = wb + (size_t)s * 64 + q * 8;
        else        src = (q < 2) ? (wb3 + (size_t)s * 16 + q * 8) : (const f16*)zpage;
        load16_lds(src, smem + 33280 + (size_t)(2560 + wvu * 64) * 16);
      }
      __syncthreads();
      // ---- compute ----
      if (!lastc){
        #pragma unroll
        for (int kx = 0; kx < 3; kx++){
          half8 bh[7], bl[7];
          #pragma unroll
          for (int nt = 0; nt < 7; nt++){
            int bs = kx * 112 + nt * 16 + l15;
            const char* bp = smem + 33280 + bs * 128;
            bh[nt] = *(const half8*)(bp + ((quad ^ (bs & 7)) << 4));
            bl[nt] = *(const half8*)(bp + (((quad + 4) ^ (bs & 7)) << 4));
          }
          #pragma unroll
          for (int mt = 0; mt < 4; mt++){
            int as = (wvu * 4 + mt) * 16 + l15 + kx;
            const char* ap = smem + as * 128;
            half8 ah = *(const half8*)(ap + ((quad ^ (as & 7)) << 4));
            half8 al = *(const half8*)(ap + (((quad + 4) ^ (as & 7)) << 4));
            #pragma unroll
            for (int nt = 0; nt < 7; nt++){
              acc[mt][nt] = __builtin_amdgcn_mfma_f32_16x16x32_f16(ah, bh[nt], acc[mt][nt], 0, 0, 0);
              acc[mt][nt] = __builtin_amdgcn_mfma_f32_16x16x32_f16(ah, bl[nt], acc[mt][nt], 0, 0, 0);
              acc[mt][nt] = __builtin_amdgcn_mfma_f32_16x16x32_f16(al, bh[nt], acc[mt][nt], 0, 0, 0);
            }
          }
        }
      } else {
        // ic 96..99 packed K: A=[hi4,hi4][lo4,0], B=[hi4,lo4][hi4,0] -> hh+hl+lh in one MFMA
        #pragma unroll
        for (int kx = 0; kx < 3; kx++){
          half8 bh[7];
          #pragma unroll
          for (int nt = 0; nt < 7; nt++){
            int bs = kx * 112 + nt * 16 + l15;
            bh[nt] = *(const half8*)(smem + 33280 + bs * 128 + ((quad ^ (bs & 7)) << 4));
          }
          #pragma unroll
          for (int mt = 0; mt < 4; mt++){
            int as = (wvu * 4 + mt) * 16 + l15 + kx;
            half8 ah = *(const half8*)(smem + as * 128 + ((quad ^ (as & 7)) << 4));
            #pragma unroll
            for (int nt = 0; nt < 7; nt++)
              acc[mt][nt] = __builtin_amdgcn_mfma_f32_16x16x32_f16(ah, bh[nt], acc[mt][nt], 0, 0, 0);
          }
        }
      }
    }
  }

  // ---------------- epilogue ----------------
  __syncthreads();
  f16* y2 = (f16*)(smem + wvu * 16896);        // per-wave [32 px][264 f16]: hi 0..127, lo 128..255
  float* mbuf = (float*)(smem + wvu * 16896);  // per-wave [32 od][33] f32 (reused AFTER y2 reads)
  int* mobj_lds = (int*)(smem + 67584);        // [256] px labels

  half8 w3h[2][4], w3l[2][4];
  #pragma unroll
  for (int odt = 0; odt < 2; odt++)
    #pragma unroll
    for (int ks = 0; ks < 4; ks++){
      const f16* wp = W3p + ((odt * 16 + l15) * 4 + ks) * 64 + quad * 8;
      w3h[odt][ks] = *(const half8*)wp;
      w3l[odt][ks] = *(const half8*)(wp + 32);
    }
  float b2v[7], s2v[7], c2v[7];
  #pragma unroll
  for (int nt = 0; nt < 7; nt++){
    int oc = min(nt * 16 + l15, 99);
    b2v[nt] = b2[oc]; s2v[nt] = s2[oc]; c2v[nt] = c2[oc];
  }
  const float inv = 1.52587890625e-05f;   // 2^-16
  float s3a = s3p[l15] * inv, c3a = c3p[l15];
  float s3b = s3p[l15 + 16] * inv, c3b = c3p[l15 + 16];

  float* moutn = mask_out + (size_t)n * 32 * 65536 + (size_t)row * 256;

  for (int pass = 0; pass < 2; pass++){
    if (lane < 32){
      floatx4 z = {0.f, 0.f, 0.f, 0.f};
      *(floatx4*)(y2 + lane * 264 + 112) = z;
      *(floatx4*)(y2 + lane * 264 + 120) = z;
      *(floatx4*)(y2 + lane * 264 + 240) = z;
      *(floatx4*)(y2 + lane * 264 + 248) = z;
    }
    #pragma unroll
    for (int mtp = 0; mtp < 2; mtp++){
      int mt = pass * 2 + mtp;
      #pragma unroll
      for (int nt = 0; nt < 7; nt++){
        #pragma unroll
        for (int r = 0; r < 4; r++){
          float yv = fmaxf(acc[mt][nt][r] * inv + b2v[nt], 0.f) * s2v[nt] + c2v[nt];
          float ys = yv * 256.f;
          f16 h = (f16)ys;
          int rr = mtp * 16 + quad * 4 + r;
          y2[rr * 264 + nt * 16 + l15] = h;
          y2[rr * 264 + 128 + nt * 16 + l15] = (f16)(ys - (float)h);
        }
      }
    }
    floatx4 macc[2][2];
    #pragma unroll
    for (int mtp = 0; mtp < 2; mtp++)
      #pragma unroll
      for (int odt = 0; odt < 2; odt++) macc[mtp][odt] = {0.f, 0.f, 0.f, 0.f};
    #pragma unroll
    for (int ks = 0; ks < 4; ks++){
      #pragma unroll
      for (int mtp = 0; mtp < 2; mtp++){
        const f16* ap = y2 + (mtp * 16 + l15) * 264 + ks * 32 + quad * 8;
        half8 ah = *(const half8*)ap;
        half8 al = *(const half8*)(ap + 128);
        #pragma unroll
        for (int odt = 0; odt < 2; odt++){
          macc[mtp][odt] = __builtin_amdgcn_mfma_f32_16x16x32_f16(ah, w3h[odt][ks], macc[mtp][odt], 0, 0, 0);
          macc[mtp][odt] = __builtin_amdgcn_mfma_f32_16x16x32_f16(ah, w3l[odt][ks], macc[mtp][odt], 0, 0, 0);
          macc[mtp][odt] = __builtin_amdgcn_mfma_f32_16x16x32_f16(al, w3h[odt][ks], macc[mtp][odt], 0, 0, 0);
        }
      }
    }
    // mask values -> per-wave LDS [32 od][33] (y2 data is dead now), then coalesced global write
    #pragma unroll
    for (int mtp = 0; mtp < 2; mtp++){
      #pragma unroll
      for (int r = 0; r < 4; r++){
        float v0 = macc[mtp][0][r] * s3a + c3a;   // od = l15
        float v1 = macc[mtp][1][r] * s3b + c3b;   // od = l15+16
        int pxl = mtp * 16 + quad * 4 + r;
        mbuf[l15 * 33 + pxl] = v0;
        mbuf[(l15 + 16) * 33 + pxl] = v1;
        float bv = v0; int bi = l15;
        if (v1 > bv){ bv = v1; bi = l15 + 16; }
        #pragma unroll
        for (int off = 1; off < 16; off <<= 1){
          float ov = __shfl_xor(bv, off, 16);
          int   oi = __shfl_xor(bi, off, 16);
          if (ov > bv || (ov == bv && oi < bi)){ bv = ov; bi = oi; }
        }
        if (l15 == 0) mobj_lds[wvu * 64 + pass * 32 + pxl] = bi;
      }
    }
    int base = wvu * 64 + pass * 32;
    #pragma unroll
    for (int i = 0; i < 4; i++){
      int od = i * 8 + (lane >> 3);
      int px4 = (lane & 7) * 4;
      floatx4 v;
      v.x = mbuf[od * 33 + px4];
      v.y = mbuf[od * 33 + px4 + 1];
      v.z = mbuf[od * 33 + px4 + 2];
      v.w = mbuf[od * 33 + px4 + 3];
      *(floatx4*)(moutn + (size_t)od * 65536 + base + px4) = v;
    }
    __syncthreads();
  }
  if (threadIdx.x < 64){
    intx4 v = ((const intx4*)mobj_lds)[threadIdx.x];
    *(intx4*)(maskobj + (size_t)n * 65536 + (size_t)row * 256 + threadIdx.x * 4) = v;
  }
}

// ---------------- per-tile segment partial sums (features resized on the fly) ----------------
__global__ __launch_bounds__(256) void k_segsum(const int* __restrict__ maskobj,
    const float* __restrict__ fsmall, float* __restrict__ psum, float* __restrict__ pcnt){
  int b = blockIdx.x; int n = b >> 8; int p0 = (b & 255) * 256;
  __shared__ float lsum[640];
  __shared__ float lcnt[32];
  for (int i = threadIdx.x; i < 640; i += 256) lsum[i] = 0.f;
  if (threadIdx.x < 32) lcnt[threadIdx.x] = 0.f;
  __syncthreads();
  int p = p0 + threadIdx.x;
  int id = maskobj[n * 65536 + p];
  atomicAdd(&lcnt[id], 1.f);
  int y = p >> 8, xo = p & 255;
  float syf = (y + 0.5f) * 0.0625f - 0.5f; int sy0 = (int)floorf(syf); float fy = syf - sy0;
  int y0 = max(sy0, 0), y1i = min(sy0 + 1, 15);
  float sxf = (xo + 0.5f) * 0.0625f - 0.5f; int sx0 = (int)floorf(sxf); float fx = sxf - sx0;
  int x0 = max(sx0, 0), x1i = min(sx0 + 1, 15);
  const float* fs = fsmall + (size_t)n * 20 * 256;
  for (int c = 0; c < 20; c++){
    const float* F = fs + c * 256;
    float v = (1.f - fy) * ((1.f - fx) * F[y0 * 16 + x0] + fx * F[y0 * 16 + x1i])
            +        fy  * ((1.f - fx) * F[y1i * 16 + x0] + fx * F[y1i * 16 + x1i]);
    atomicAdd(&lsum[id * 20 + c], v);
  }
  __syncthreads();
  for (int i = threadIdx.x; i < 640; i += 256) psum[(size_t)b * 640 + i] = lsum[i];
  if (threadIdx.x < 32) pcnt[(size_t)b * 32 + threadIdx.x] = lcnt[threadIdx.x];
}

// ---------------- reduce partials -> sums/cnt ----------------
__global__ __launch_bounds__(256) void k_reduce(const float* __restrict__ psum,
    const float* __restrict__ pcnt, float* __restrict__ sums, float* __restrict__ cnt){
  int idx = blockIdx.x * 256 + threadIdx.x;
  int n = idx / 640, r = idx % 640;
  float s = 0.f;
  for (int b = 0; b < 256; b++) s += psum[((size_t)n * 256 + b) * 640 + r];
  sums[idx] = s;
  if (idx < 256){
    int n2 = idx >> 5, s2 = idx & 31;
    float c = 0.f;
    for (int b = 0; b < 256; b++) c += pcnt[((size_t)n2 * 256 + b) * 32 + s2];
    cnt[idx] = c;
  }
}

// ---------------- means + cls_fea ----------------
__global__ __launch_bounds__(256) void k_means(const float* __restrict__ sums,
    const float* __restrict__ cnt, float* __restrict__ means, float* __restrict__ cls_fea){
  __shared__ float lm[5120];
  __shared__ float lc[256];
  int s = threadIdx.x;
  lc[s] = cnt[s];
  float c = fmaxf(lc[s], 1.f);
  for (int ch = 0; ch < 20; ch++){
    float m = sums[s * 20 + ch] / c;
    lm[s * 20 + ch] = m;
    means[s * 20 + ch] = m;
  }
  __syncthreads();
  if (s < 160){
    int n = s / 20, ch = s % 20;
    float m = -3.4e38f;
    for (int seg = 0; seg < 32; seg++){
      int g = n * 32 + seg;
      if (lc[g] > 0.f) m = fmaxf(m, lm[g * 20 + ch]);
    }
    cls_fea[s] = m;
  }
}

// ---------------- scatter means -> features output ----------------
__global__ __launch_bounds__(256) void k_scatter(const int* __restrict__ maskobj,
    const float* __restrict__ means, float* __restrict__ feat_out){
  int idx = blockIdx.x * 256 + threadIdx.x;
  int n = idx >> 16, p = idx & 65535;
  int id = maskobj[idx];
  const float* mrow = means + (n * 32 + id) * 20;
  #pragma unroll
  for (int c = 0; c < 20; c++)
    feat_out[((size_t)n * 20 + c) * 65536 + p] = mrow[c];
}

extern "C" void kernel_launch(void* const* d_in, const int* in_sizes, int n_in,
                              void* d_out, int out_size, void* d_ws, size_t ws_size,
                              hipStream_t stream) {
  const float* x   = (const float*)d_in[0];
  const float* x4  = (const float*)d_in[1];
  const float* Wc  = (const float*)d_in[2];
  const float* W1  = (const float*)d_in[3];
  const float* b1  = (const float*)d_in[4];
  const float* g1  = (const float*)d_in[5];
  const float* be1 = (const float*)d_in[6];
  const float* m1  = (const float*)d_in[7];
  const float* v1  = (const float*)d_in[8];
  const float* W2  = (const float*)d_in[9];
  const float* b2  = (const float*)d_in[10];
  const float* g2  = (const float*)d_in[11];
  const float* be2 = (const float*)d_in[12];
  const float* m2  = (const float*)d_in[13];
  const float* v2  = (const float*)d_in[14];
  const float* W3  = (const float*)d_in[15];
  const float* b3  = (const float*)d_in[16];
  const float* g3  = (const float*)d_in[17];
  const float* be3 = (const float*)d_in[18];
  const float* m3  = (const float*)d_in[19];
  const float* v3  = (const float*)d_in[20];

  float* out = (float*)d_out;
  float* cls_out  = out;                  // [8,20]
  float* clsf_out = out + 160;            // [8,20]
  float* feat_out = out + 320;            // [8,20,256,256]
  float* mask_out = out + 320 + 10485760; // [8,32,256,256]

  float* wsf = (float*)d_ws;
  float* fsmall  = wsf;                          // 40,960 f32
  int*   maskobj = (int*)(wsf + 40960);          // 524,288 int
  float* pcnt    = wsf + 565248;                 // 65,536 f32
  float* sums    = wsf + 630784;                 // 5,120
  float* cnt     = wsf + 635904;                 // 256
  float* means   = wsf + 636160;                 // 5,120
  f16*   W2a     = (f16*)(wsf + 641280);         // 193,536 f16 -> 96,768 f32
  f16*   W2c3    = (f16*)(wsf + 738048);         //  16,128 f16 ->  8,064 f32
  f16*   W3p     = (f16*)(wsf + 746112);         //   8,192 f16 ->  4,096 f32
  float* s1      = wsf + 750208;  float* c1 = s1 + 100;
  float* s2      = c1 + 100;      float* c2 = s2 + 100;
  float* s3p     = c2 + 100;      float* c3p = s3p + 32;   // ends 750,740
  float* zpage   = wsf + 750752;                 // 64 f32 zeros (16B aligned)
  f16*   y1a     = (f16*)(wsf + 750848);         // 100,663,296 f16 = 201.3 MB
  f16*   y1c3    = (f16*)(wsf + 51082496);       //   8,388,608 f16 =  16.8 MB (ends 55,276,800 f32)
  float* psum    = (float*)y1a;                  // overlay: y1 dead before segsum

  hipMemsetAsync(zpage, 0, 256, stream);
  k_prep<<<852, 256, 0, stream>>>(W2, W3, b3, g1, be1, m1, v1, g2, be2, m2, v2,
                                  g3, be3, m3, v3, W2a, W2c3, W3p, s1, c1, s2, c2, s3p, c3p);
  k_classifier<<<160, 256, 0, stream>>>(x4, Wc, fsmall, cls_out);
  k_conv1<<<dim3(16, 16, 8), 256, 0, stream>>>(x, W1, b1, s1, c1, y1a, y1c3);
  k_conv2<<<dim3(256, 8), 256, 0, stream>>>(y1a, y1c3, W2a, W2c3, W3p, b2, s2, c2, s3p, c3p,
                                            zpage, mask_out, maskobj);
  k_segsum<<<2048, 256, 0, stream>>>(maskobj, fsmall, psum, pcnt);
  k_reduce<<<20, 256, 0, stream>>>(psum, pcnt, sums, cnt);
  k_means<<<1, 256, 0, stream>>>(sums, cnt, means, clsf_out);
  k_scatter<<<2048, 256, 0, stream>>>(maskobj, means, feat_out);
}

// Round 6
// 945.391 us; speedup vs baseline: 3.6936x; 2.1516x over previous
//
#include <hip/hip_runtime.h>

#define BN_EPS 1e-5f

typedef float floatx4 __attribute__((ext_vector_type(4)));
typedef int   intx4   __attribute__((ext_vector_type(4)));
typedef _Float16 half8 __attribute__((ext_vector_type(8)));
typedef _Float16 f16;

__device__ __forceinline__ void load16_lds(const void* gsrc, void* lds){
  __builtin_amdgcn_global_load_lds((const __attribute__((address_space(1))) unsigned int*)gsrc,
                                   (__attribute__((address_space(3))) unsigned int*)lds, 16, 0, 0);
}

// ---------------- prep: planar packed weights (x256 hi/lo f16) + BN consts ----------------
// W2a: [c(3)][ky(3)][kx(3)][oc(112)][hi32|lo32]           = 193,536 f16
// W2c3:[ky(3)][kx(3)][oc(112)][g0:hi4,lo4 | g1:hi4,0x4]   =  16,128 f16
// W3p: [od(32)][c(4)][hi32|lo32]                          =   8,192 f16
__global__ __launch_bounds__(256) void k_prep(
    const float* __restrict__ W2, const float* __restrict__ W3, const float* __restrict__ b3,
    const float* __restrict__ g1, const float* __restrict__ be1, const float* __restrict__ m1, const float* __restrict__ v1,
    const float* __restrict__ g2, const float* __restrict__ be2, const float* __restrict__ m2, const float* __restrict__ v2,
    const float* __restrict__ g3, const float* __restrict__ be3, const float* __restrict__ m3, const float* __restrict__ v3,
    f16* __restrict__ W2a, f16* __restrict__ W2c3, f16* __restrict__ W3p,
    float* __restrict__ s1, float* __restrict__ c1, float* __restrict__ s2, float* __restrict__ c2,
    float* __restrict__ s3p, float* __restrict__ c3p){
  int idx = blockIdx.x * 256 + threadIdx.x;
  if (idx < 193536){
    int e = idx & 63; int s6 = idx >> 6;             // s6 < 3024
    int oc = s6 % 112, k9 = (s6 / 112) % 9, c = s6 / 1008;
    int hl = e >> 5, j = e & 31, ic = c * 32 + j;
    float v = (oc < 100) ? W2[(oc * 100 + ic) * 9 + k9] * 256.f : 0.f;
    f16 h = (f16)v;
    W2a[idx] = hl ? (f16)(v - (float)h) : h;
  } else if (idx < 193536 + 16128){
    int t = idx - 193536;
    int e = t & 15; int s4 = t >> 4;                 // s4 < 1008
    int oc = s4 % 112, k9 = s4 / 112;
    int g = e >> 3, ee = e & 7, ic = 96 + (ee & 3);
    float v = (oc < 100) ? W2[(oc * 100 + ic) * 9 + k9] * 256.f : 0.f;
    f16 h = (f16)v;
    f16 l = (f16)(v - (float)h);
    f16 outv;
    if (g == 0) outv = (ee < 4) ? h : l;
    else        outv = (ee < 4) ? h : (f16)0.f;
    W2c3[t] = outv;
  } else if (idx < 193536 + 16128 + 8192){
    int j = idx - 193536 - 16128;
    int od = j >> 8, t = j & 255;
    int c = t >> 6, u = t & 63, hl = u >> 5, jj = u & 31;
    int oc = c * 32 + jj;
    float v = (oc < 100) ? W3[od * 100 + oc] * 256.f : 0.f;
    f16 h = (f16)v;
    W3p[j] = hl ? (f16)(v - (float)h) : h;
  } else if (idx < 193536 + 16128 + 8192 + 256){
    int j = idx - 193536 - 16128 - 8192;
    if (j < 100){ float s = g1[j] * rsqrtf(v1[j] + BN_EPS); s1[j] = s; c1[j] = be1[j] - m1[j] * s; }
    else if (j < 200){ int t = j - 100; float s = g2[t] * rsqrtf(v2[t] + BN_EPS); s2[t] = s; c2[t] = be2[t] - m2[t] * s; }
    else if (j < 232){ int t = j - 200; float s = g3[t] * rsqrtf(v3[t] + BN_EPS); s3p[t] = s; c3p[t] = (b3[t] - m3[t]) * s + be3[t]; }
  }
}

// ---------------- classifier 1x1 conv + spatial max (cls) ----------------
__global__ __launch_bounds__(256) void k_classifier(const float* __restrict__ x4,
    const float* __restrict__ Wc, float* __restrict__ fsmall, float* __restrict__ cls){
  int nc = blockIdx.x; int n = nc / 20, c = nc % 20;
  __shared__ float wc[512];
  for (int k = threadIdx.x; k < 512; k += 256) wc[k] = Wc[c * 512 + k];
  __syncthreads();
  int p = threadIdx.x;
  const float* xp = x4 + (size_t)n * 512 * 256 + p;
  float acc = 0.f;
  #pragma unroll 8
  for (int k = 0; k < 512; k++) acc = fmaf(xp[(size_t)k * 256], wc[k], acc);
  fsmall[((size_t)n * 20 + c) * 256 + p] = acc;
  float m = acc;
  for (int off = 32; off > 0; off >>= 1) m = fmaxf(m, __shfl_down(m, off, 64));
  __shared__ float wmax[4];
  if ((threadIdx.x & 63) == 0) wmax[threadIdx.x >> 6] = m;
  __syncthreads();
  if (threadIdx.x == 0)
    cls[n * 20 + c] = fmaxf(fmaxf(wmax[0], wmax[1]), fmaxf(wmax[2], wmax[3]));
}

// ---------------- conv1 3x3 (3->100) + ReLU + BN1 -> y1 planar hi/lo f16 (x256), fused resize ----
// y1a plane (c<3): [n][c][p][hi32|lo32];  y1c3: [n][p][g0:hi4,hi4 | g1:lo4,0x4]
__global__ __launch_bounds__(256) void k_conv1(const float* __restrict__ x,
    const float* __restrict__ W1, const float* __restrict__ b1,
    const float* __restrict__ s1, const float* __restrict__ c1,
    f16* __restrict__ y1a, f16* __restrict__ y1c3){
  int n = blockIdx.z; int ty0 = blockIdx.y * 16, tx0 = blockIdx.x * 16;
  __shared__ float tile[3][18][19];
  const float w4[4] = {0.125f, 0.375f, 0.375f, 0.125f};
  for (int i = threadIdx.x; i < 972; i += 256){
    int ch = i / 324, r = i % 324;
    int yy = ty0 + r / 18 - 1, xx = tx0 + r % 18 - 1;
    float val = 0.f;
    if (yy >= 0 && yy < 256 && xx >= 0 && xx < 256){
      const float* src = x + (size_t)(n * 3 + ch) * 262144;
      float acc = 0.f, ws = 0.f;
      #pragma unroll
      for (int ty = 0; ty < 4; ty++){
        int sy = 2 * yy - 1 + ty; if (sy < 0 || sy > 511) continue;
        #pragma unroll
        for (int tx = 0; tx < 4; tx++){
          int sx = 2 * xx - 1 + tx; if (sx < 0 || sx > 511) continue;
          float w = w4[ty] * w4[tx];
          acc += w * src[sy * 512 + sx]; ws += w;
        }
      }
      val = acc / ws;
    }
    tile[ch][r / 18][r % 18] = val;
  }
  __syncthreads();
  int ly = threadIdx.x >> 4, lx = threadIdx.x & 15;
  float in[3][9];
  #pragma unroll
  for (int ch = 0; ch < 3; ch++)
    #pragma unroll
    for (int k = 0; k < 9; k++) in[ch][k] = tile[ch][ly + k / 3][lx + k % 3];
  int p = (ty0 + ly) * 256 + tx0 + lx;
  for (int c = 0; c < 3; c++){
    float acc[32];
    #pragma unroll
    for (int o = 0; o < 32; o++) acc[o] = 0.f;
    #pragma unroll
    for (int ch = 0; ch < 3; ch++)
      #pragma unroll
      for (int o = 0; o < 32; o++)
        #pragma unroll
        for (int k = 0; k < 9; k++)
          acc[o] = fmaf(in[ch][k], W1[((c * 32 + o) * 3 + ch) * 9 + k], acc[o]);
    f16* rec = y1a + ((size_t)(n * 3 + c) * 65536 + p) * 64;
    #pragma unroll
    for (int g = 0; g < 4; g++){
      half8 hv, lv;
      #pragma unroll
      for (int e = 0; e < 8; e++){
        int j = g * 8 + e, oc = c * 32 + j;
        float v = (fmaxf(acc[j] + b1[oc], 0.f) * s1[oc] + c1[oc]) * 256.f;
        f16 h = (f16)v;
        hv[e] = h; lv[e] = (f16)(v - (float)h);
      }
      *(half8*)(rec + g * 8) = hv;
      *(half8*)(rec + 32 + g * 8) = lv;
    }
  }
  float a3[4];
  #pragma unroll
  for (int o = 0; o < 4; o++) a3[o] = 0.f;
  #pragma unroll
  for (int ch = 0; ch < 3; ch++)
    #pragma unroll
    for (int o = 0; o < 4; o++)
      #pragma unroll
      for (int k = 0; k < 9; k++)
        a3[o] = fmaf(in[ch][k], W1[((96 + o) * 3 + ch) * 9 + k], a3[o]);
  half8 g0, g1v;
  #pragma unroll
  for (int e = 0; e < 8; e++){
    int oc = 96 + (e & 3);
    float v = (fmaxf(a3[e & 3] + b1[oc], 0.f) * s1[oc] + c1[oc]) * 256.f;
    f16 h = (f16)v;
    g0[e] = h;
    g1v[e] = (e < 4) ? (f16)(v - (float)h) : (f16)0.f;
  }
  f16* rec3 = y1c3 + ((size_t)n * 65536 + p) * 16;
  *(half8*)(rec3) = g0;
  *(half8*)(rec3 + 8) = g1v;
}

// ---------------- conv2 3x3 (100->100) split-f16 MFMA + BN2 + conv3(1x1,split) + BN3 + argmax ----
// 512 threads, 8 waves; wave w computes px [w*32, w*32+32) x 112 oc => acc[2][7] (56 VGPRs, no spill)
__global__ __launch_bounds__(512, 2) void k_conv2(
    const f16* __restrict__ y1a, const f16* __restrict__ y1c3,
    const f16* __restrict__ W2a, const f16* __restrict__ W2c3, const f16* __restrict__ W3p,
    const float* __restrict__ b2, const float* __restrict__ s2, const float* __restrict__ c2,
    const float* __restrict__ s3p, const float* __restrict__ c3p,
    const float* __restrict__ zpage,
    float* __restrict__ mask_out, int* __restrict__ maskobj){
  __shared__ __align__(16) char smem[76288];   // A: 260 slots x 128B; B at +33280: 336 slots x 128B
  int n = blockIdx.y;
  int bid = blockIdx.x;
  int row = ((bid & 7) << 5) + ((bid >> 3) & 31);   // 32-row bands per XCD for halo L2 reuse
  int lane = threadIdx.x & 63;
  int wvu = __builtin_amdgcn_readfirstlane(threadIdx.x >> 6);  // 0..7
  int l15 = lane & 15, quad = lane >> 4;

  floatx4 acc[2][7];
  #pragma unroll
  for (int mt = 0; mt < 2; mt++)
    #pragma unroll
    for (int nt = 0; nt < 7; nt++) acc[mt][nt] = {0.f, 0.f, 0.f, 0.f};

  for (int c = 0; c < 4; c++){
    bool lastc = (c == 3);
    for (int ky = 0; ky < 3; ky++){
      __syncthreads();
      int yy = row + ky - 1;
      bool rowOOB = (yy < 0) || (yy > 255);
      const f16* rb  = y1a + ((size_t)(n * 3 + c) * 65536 + (size_t)yy * 256) * 64;
      const f16* rb3 = y1c3 + ((size_t)n * 65536 + (size_t)yy * 256) * 16;
      // ---- stage A: 260 slots x 8 granules = 2080, contiguous source ----
      #pragma unroll
      for (int it = 0; it < 4; it++){
        int G = it * 512 + threadIdx.x;
        int s = G >> 3, p = G & 7, q = p ^ (s & 7);
        int xx = s - 1;
        const f16* src;
        if (rowOOB || (unsigned)xx >= 256u) src = (const f16*)zpage;
        else if (!lastc)                    src = rb + (size_t)xx * 64 + q * 8;
        else                                src = (q < 2) ? (rb3 + (size_t)xx * 16 + q * 8) : (const f16*)zpage;
        load16_lds(src, smem + (size_t)(it * 512 + wvu * 64) * 16);
      }
      if (threadIdx.x < 32){
        int G = 2048 + threadIdx.x;
        int s = G >> 3, p = G & 7, q = p ^ (s & 7);
        int xx = s - 1;
        const f16* src;
        if (rowOOB || (unsigned)xx >= 256u) src = (const f16*)zpage;
        else if (!lastc)                    src = rb + (size_t)xx * 64 + q * 8;
        else                                src = (q < 2) ? (rb3 + (size_t)xx * 16 + q * 8) : (const f16*)zpage;
        load16_lds(src, smem + (size_t)2048 * 16);
      }
      // ---- stage B: 336 slots (kx*112+oc) x 8 granules = 2688, contiguous source ----
      const f16* wb  = W2a + (size_t)(c * 9 + ky * 3) * 112 * 64;
      const f16* wb3 = W2c3 + (size_t)(ky * 3) * 112 * 16;
      #pragma unroll
      for (int it = 0; it < 5; it++){
        int G = it * 512 + threadIdx.x;
        int s = G >> 3, p = G & 7, q = p ^ (s & 7);
        const f16* src;
        if (!lastc) src = wb + (size_t)s * 64 + q * 8;
        else        src = (q < 2) ? (wb3 + (size_t)s * 16 + q * 8) : (const f16*)zpage;
        load16_lds(src, smem + 33280 + (size_t)(it * 512 + wvu * 64) * 16);
      }
      if (threadIdx.x < 128){
        int G = 2560 + threadIdx.x;
        int s = G >> 3, p = G & 7, q = p ^ (s & 7);
        const f16* src;
        if (!lastc) src = wb + (size_t)s * 64 + q * 8;
        else        src = (q < 2) ? (wb3 + (size_t)s * 16 + q * 8) : (const f16*)zpage;
        load16_lds(src, smem + 33280 + (size_t)(2560 + wvu * 64) * 16);
      }
      __syncthreads();
      // ---- compute ----
      if (!lastc){
        #pragma unroll
        for (int kx = 0; kx < 3; kx++){
          half8 bh[7], bl[7];
          #pragma unroll
          for (int nt = 0; nt < 7; nt++){
            int bs = kx * 112 + nt * 16 + l15;
            const char* bp = smem + 33280 + bs * 128;
            bh[nt] = *(const half8*)(bp + ((quad ^ (bs & 7)) << 4));
            bl[nt] = *(const half8*)(bp + (((quad + 4) ^ (bs & 7)) << 4));
          }
          #pragma unroll
          for (int mt = 0; mt < 2; mt++){
            int as = (wvu * 2 + mt) * 16 + l15 + kx;
            const char* ap = smem + as * 128;
            half8 ah = *(const half8*)(ap + ((quad ^ (as & 7)) << 4));
            half8 al = *(const half8*)(ap + (((quad + 4) ^ (as & 7)) << 4));
            #pragma unroll
            for (int nt = 0; nt < 7; nt++){
              acc[mt][nt] = __builtin_amdgcn_mfma_f32_16x16x32_f16(ah, bh[nt], acc[mt][nt], 0, 0, 0);
              acc[mt][nt] = __builtin_amdgcn_mfma_f32_16x16x32_f16(ah, bl[nt], acc[mt][nt], 0, 0, 0);
              acc[mt][nt] = __builtin_amdgcn_mfma_f32_16x16x32_f16(al, bh[nt], acc[mt][nt], 0, 0, 0);
            }
          }
        }
      } else {
        // ic 96..99 packed K: A=[hi4,hi4][lo4,0], B=[hi4,lo4][hi4,0] -> hh+hl+lh in one MFMA
        #pragma unroll
        for (int kx = 0; kx < 3; kx++){
          half8 bh[7];
          #pragma unroll
          for (int nt = 0; nt < 7; nt++){
            int bs = kx * 112 + nt * 16 + l15;
            bh[nt] = *(const half8*)(smem + 33280 + bs * 128 + ((quad ^ (bs & 7)) << 4));
          }
          #pragma unroll
          for (int mt = 0; mt < 2; mt++){
            int as = (wvu * 2 + mt) * 16 + l15 + kx;
            half8 ah = *(const half8*)(smem + as * 128 + ((quad ^ (as & 7)) << 4));
            #pragma unroll
            for (int nt = 0; nt < 7; nt++)
              acc[mt][nt] = __builtin_amdgcn_mfma_f32_16x16x32_f16(ah, bh[nt], acc[mt][nt], 0, 0, 0);
          }
        }
      }
    }
  }

  // ---------------- epilogue (per-wave private LDS region; barrier only before & at end) --------
  __syncthreads();
  f16*   y2w  = (f16*)(smem + wvu * 8448);     // [16 px][264 f16]: hi 0..127, lo 128..255
  float* mbuf = (float*)(smem + wvu * 8448);   // [32 od][17 f32] (reused after y2 reads)
  int* mobj_lds = (int*)(smem + 67584);        // [256] px labels

  float b2v[7], s2v[7], c2v[7];
  #pragma unroll
  for (int nt = 0; nt < 7; nt++){
    int oc = min(nt * 16 + l15, 99);
    b2v[nt] = b2[oc]; s2v[nt] = s2[oc]; c2v[nt] = c2[oc];
  }
  const float inv = 1.52587890625e-05f;   // 2^-16
  float s3a = s3p[l15] * inv, c3a = c3p[l15];
  float s3b = s3p[l15 + 16] * inv, c3b = c3p[l15 + 16];

  float* moutn = mask_out + (size_t)n * 32 * 65536 + (size_t)row * 256;

  for (int sp = 0; sp < 2; sp++){
    int pxbase = (wvu * 2 + sp) * 16;
    if (lane < 16){
      floatx4 z = {0.f, 0.f, 0.f, 0.f};
      *(floatx4*)(y2w + lane * 264 + 112) = z;
      *(floatx4*)(y2w + lane * 264 + 120) = z;
      *(floatx4*)(y2w + lane * 264 + 240) = z;
      *(floatx4*)(y2w + lane * 264 + 248) = z;
    }
    #pragma unroll
    for (int nt = 0; nt < 7; nt++){
      #pragma unroll
      for (int r = 0; r < 4; r++){
        float yv = fmaxf(acc[sp][nt][r] * inv + b2v[nt], 0.f) * s2v[nt] + c2v[nt];
        float ys = yv * 256.f;
        f16 h = (f16)ys;
        int rr = quad * 4 + r;
        y2w[rr * 264 + nt * 16 + l15] = h;
        y2w[rr * 264 + 128 + nt * 16 + l15] = (f16)(ys - (float)h);
      }
    }
    floatx4 macc[2];
    macc[0] = {0.f, 0.f, 0.f, 0.f};
    macc[1] = {0.f, 0.f, 0.f, 0.f};
    #pragma unroll
    for (int ks = 0; ks < 4; ks++){
      const f16* ap = y2w + l15 * 264 + ks * 32 + quad * 8;
      half8 ah = *(const half8*)ap;
      half8 al = *(const half8*)(ap + 128);
      #pragma unroll
      for (int odt = 0; odt < 2; odt++){
        const f16* wp = W3p + ((odt * 16 + l15) * 4 + ks) * 64 + quad * 8;
        half8 w3h = *(const half8*)wp;
        half8 w3l = *(const half8*)(wp + 32);
        macc[odt] = __builtin_amdgcn_mfma_f32_16x16x32_f16(ah, w3h, macc[odt], 0, 0, 0);
        macc[odt] = __builtin_amdgcn_mfma_f32_16x16x32_f16(ah, w3l, macc[odt], 0, 0, 0);
        macc[odt] = __builtin_amdgcn_mfma_f32_16x16x32_f16(al, w3h, macc[odt], 0, 0, 0);
      }
    }
    #pragma unroll
    for (int r = 0; r < 4; r++){
      float v0 = macc[0][r] * s3a + c3a;   // od = l15
      float v1 = macc[1][r] * s3b + c3b;   // od = l15+16
      int rr = quad * 4 + r;
      mbuf[l15 * 17 + rr] = v0;
      mbuf[(l15 + 16) * 17 + rr] = v1;
      float bv = v0; int bi = l15;
      if (v1 > bv){ bv = v1; bi = l15 + 16; }
      #pragma unroll
      for (int off = 1; off < 16; off <<= 1){
        float ov = __shfl_xor(bv, off, 16);
        int   oi = __shfl_xor(bi, off, 16);
        if (ov > bv || (ov == bv && oi < bi)){ bv = ov; bi = oi; }
      }
      if (l15 == 0) mobj_lds[wvu * 32 + sp * 16 + rr] = bi;
    }
    // coalesced mask write: 16 px (64 B) contiguous per od
    #pragma unroll
    for (int i = 0; i < 2; i++){
      int od = i * 16 + (lane >> 2);
      int px4 = (lane & 3) * 4;
      floatx4 v;
      v.x = mbuf[od * 17 + px4];
      v.y = mbuf[od * 17 + px4 + 1];
      v.z = mbuf[od * 17 + px4 + 2];
      v.w = mbuf[od * 17 + px4 + 3];
      *(floatx4*)(moutn + (size_t)od * 65536 + pxbase + px4) = v;
    }
  }
  __syncthreads();
  if (threadIdx.x < 64){
    intx4 v = ((const intx4*)mobj_lds)[threadIdx.x];
    *(intx4*)(maskobj + (size_t)n * 65536 + (size_t)row * 256 + threadIdx.x * 4) = v;
  }
}

// ---------------- per-tile segment partial sums (features resized on the fly) ----------------
__global__ __launch_bounds__(256) void k_segsum(const int* __restrict__ maskobj,
    const float* __restrict__ fsmall, float* __restrict__ psum, float* __restrict__ pcnt){
  int b = blockIdx.x; int n = b >> 8; int p0 = (b & 255) * 256;
  __shared__ float lsum[640];
  __shared__ float lcnt[32];
  for (int i = threadIdx.x; i < 640; i += 256) lsum[i] = 0.f;
  if (threadIdx.x < 32) lcnt[threadIdx.x] = 0.f;
  __syncthreads();
  int p = p0 + threadIdx.x;
  int id = maskobj[n * 65536 + p];
  atomicAdd(&lcnt[id], 1.f);
  int y = p >> 8, xo = p & 255;
  float syf = (y + 0.5f) * 0.0625f - 0.5f; int sy0 = (int)floorf(syf); float fy = syf - sy0;
  int y0 = max(sy0, 0), y1i = min(sy0 + 1, 15);
  float sxf = (xo + 0.5f) * 0.0625f - 0.5f; int sx0 = (int)floorf(sxf); float fx = sxf - sx0;
  int x0 = max(sx0, 0), x1i = min(sx0 + 1, 15);
  const float* fs = fsmall + (size_t)n * 20 * 256;
  for (int c = 0; c < 20; c++){
    const float* F = fs + c * 256;
    float v = (1.f - fy) * ((1.f - fx) * F[y0 * 16 + x0] + fx * F[y0 * 16 + x1i])
            +        fy  * ((1.f - fx) * F[y1i * 16 + x0] + fx * F[y1i * 16 + x1i]);
    atomicAdd(&lsum[id * 20 + c], v);
  }
  __syncthreads();
  for (int i = threadIdx.x; i < 640; i += 256) psum[(size_t)b * 640 + i] = lsum[i];
  if (threadIdx.x < 32) pcnt[(size_t)b * 32 + threadIdx.x] = lcnt[threadIdx.x];
}

// ---------------- reduce partials -> sums/cnt ----------------
__global__ __launch_bounds__(256) void k_reduce(const float* __restrict__ psum,
    const float* __restrict__ pcnt, float* __restrict__ sums, float* __restrict__ cnt){
  int idx = blockIdx.x * 256 + threadIdx.x;
  int n = idx / 640, r = idx % 640;
  float s = 0.f;
  for (int b = 0; b < 256; b++) s += psum[((size_t)n * 256 + b) * 640 + r];
  sums[idx] = s;
  if (idx < 256){
    int n2 = idx >> 5, s2 = idx & 31;
    float c = 0.f;
    for (int b = 0; b < 256; b++) c += pcnt[((size_t)n2 * 256 + b) * 32 + s2];
    cnt[idx] = c;
  }
}

// ---------------- means + cls_fea ----------------
__global__ __launch_bounds__(256) void k_means(const float* __restrict__ sums,
    const float* __restrict__ cnt, float* __restrict__ means, float* __restrict__ cls_fea){
  __shared__ float lm[5120];
  __shared__ float lc[256];
  int s = threadIdx.x;
  lc[s] = cnt[s];
  float c = fmaxf(lc[s], 1.f);
  for (int ch = 0; ch < 20; ch++){
    float m = sums[s * 20 + ch] / c;
    lm[s * 20 + ch] = m;
    means[s * 20 + ch] = m;
  }
  __syncthreads();
  if (s < 160){
    int n = s / 20, ch = s % 20;
    float m = -3.4e38f;
    for (int seg = 0; seg < 32; seg++){
      int g = n * 32 + seg;
      if (lc[g] > 0.f) m = fmaxf(m, lm[g * 20 + ch]);
    }
    cls_fea[s] = m;
  }
}

// ---------------- scatter means -> features output ----------------
__global__ __launch_bounds__(256) void k_scatter(const int* __restrict__ maskobj,
    const float* __restrict__ means, float* __restrict__ feat_out){
  int idx = blockIdx.x * 256 + threadIdx.x;
  int n = idx >> 16, p = idx & 65535;
  int id = maskobj[idx];
  const float* mrow = means + (n * 32 + id) * 20;
  #pragma unroll
  for (int c = 0; c < 20; c++)
    feat_out[((size_t)n * 20 + c) * 65536 + p] = mrow[c];
}

extern "C" void kernel_launch(void* const* d_in, const int* in_sizes, int n_in,
                              void* d_out, int out_size, void* d_ws, size_t ws_size,
                              hipStream_t stream) {
  const float* x   = (const float*)d_in[0];
  const float* x4  = (const float*)d_in[1];
  const float* Wc  = (const float*)d_in[2];
  const float* W1  = (const float*)d_in[3];
  const float* b1  = (const float*)d_in[4];
  const float* g1  = (const float*)d_in[5];
  const float* be1 = (const float*)d_in[6];
  const float* m1  = (const float*)d_in[7];
  const float* v1  = (const float*)d_in[8];
  const float* W2  = (const float*)d_in[9];
  const float* b2  = (const float*)d_in[10];
  const float* g2  = (const float*)d_in[11];
  const float* be2 = (const float*)d_in[12];
  const float* m2  = (const float*)d_in[13];
  const float* v2  = (const float*)d_in[14];
  const float* W3  = (const float*)d_in[15];
  const float* b3  = (const float*)d_in[16];
  const float* g3  = (const float*)d_in[17];
  const float* be3 = (const float*)d_in[18];
  const float* m3  = (const float*)d_in[19];
  const float* v3  = (const float*)d_in[20];

  float* out = (float*)d_out;
  float* cls_out  = out;                  // [8,20]
  float* clsf_out = out + 160;            // [8,20]
  float* feat_out = out + 320;            // [8,20,256,256]
  float* mask_out = out + 320 + 10485760; // [8,32,256,256]

  float* wsf = (float*)d_ws;
  float* fsmall  = wsf;                          // 40,960 f32
  int*   maskobj = (int*)(wsf + 40960);          // 524,288 int
  float* pcnt    = wsf + 565248;                 // 65,536 f32
  float* sums    = wsf + 630784;                 // 5,120
  float* cnt     = wsf + 635904;                 // 256
  float* means   = wsf + 636160;                 // 5,120
  f16*   W2a     = (f16*)(wsf + 641280);         // 193,536 f16 -> 96,768 f32
  f16*   W2c3    = (f16*)(wsf + 738048);         //  16,128 f16 ->  8,064 f32
  f16*   W3p     = (f16*)(wsf + 746112);         //   8,192 f16 ->  4,096 f32
  float* s1      = wsf + 750208;  float* c1 = s1 + 100;
  float* s2      = c1 + 100;      float* c2 = s2 + 100;
  float* s3p     = c2 + 100;      float* c3p = s3p + 32;   // ends 750,740
  float* zpage   = wsf + 750752;                 // 64 f32 zeros (16B aligned)
  f16*   y1a     = (f16*)(wsf + 750848);         // 100,663,296 f16 = 201.3 MB
  f16*   y1c3    = (f16*)(wsf + 51082496);       //   8,388,608 f16 =  16.8 MB (ends 55,276,800 f32)
  float* psum    = (float*)y1a;                  // overlay: y1 dead before segsum

  hipMemsetAsync(zpage, 0, 256, stream);
  k_prep<<<852, 256, 0, stream>>>(W2, W3, b3, g1, be1, m1, v1, g2, be2, m2, v2,
                                  g3, be3, m3, v3, W2a, W2c3, W3p, s1, c1, s2, c2, s3p, c3p);
  k_classifier<<<160, 256, 0, stream>>>(x4, Wc, fsmall, cls_out);
  k_conv1<<<dim3(16, 16, 8), 256, 0, stream>>>(x, W1, b1, s1, c1, y1a, y1c3);
  k_conv2<<<dim3(256, 8), 512, 0, stream>>>(y1a, y1c3, W2a, W2c3, W3p, b2, s2, c2, s3p, c3p,
                                            zpage, mask_out, maskobj);
  k_segsum<<<2048, 256, 0, stream>>>(maskobj, fsmall, psum, pcnt);
  k_reduce<<<20, 256, 0, stream>>>(psum, pcnt, sums, cnt);
  k_means<<<1, 256, 0, stream>>>(sums, cnt, means, clsf_out);
  k_scatter<<<2048, 256, 0, stream>>>(maskobj, means, feat_out);
}